// Round 7
// baseline (444.807 us; speedup 1.0000x reference)
//
#include <hip/hip_runtime.h>

// FuncConv: out = select(inv, mlp_inv(res), res); res = mlp_and(mean_dst(msg));
// msg = select(r, mlp_inv(feat[src]), feat[src]).
// R6: (a) MLP pass was latency-bound at 24% occupancy (40 KB LDS weight cache
//     + staging barrier, 2 blocks/CU). Weights are block-invariant -> pre-pack
//     bf16 MFMA B-frags ONCE in global (prep_frags_k); mlp3_t reads them via
//     L1/L2-hot coalesced 16B loads. LDS 56->16 KB, no barrier, 3 blocks/CU.
// (b) inv-scan kernels fused into the coarse CSR kernels (3 fewer launches).
//
// ws: featb[N*H bf16 | resb aliases] invb[N*H bf16] neighb[N*H bf16]
//     offsets[N+1] ilist[N] irank[N] ebuf[E] packed[E]
//     frg[80*512 us] chist[256] cbase[257] ccur[256] bsumI[256] icnt[1]

#define H 128
#define HH 64
#define CHUNK 2048
#define NW 8      // waves per MLP block
#define BSH 9     // log2 nodes per coarse bucket
#define BSZ 512   // nodes per coarse bucket
#define ACH 2048  // edges per coarse block

typedef float f32x4 __attribute__((ext_vector_type(4)));
typedef __bf16 bf16x8 __attribute__((ext_vector_type(8)));
typedef unsigned short us8 __attribute__((ext_vector_type(8)));
typedef unsigned short ushort_t;

__device__ __forceinline__ unsigned short bfbits(float f) {
    __bf16 h = (__bf16)f;                       // RNE convert
    return __builtin_bit_cast(unsigned short, h);
}
__device__ __forceinline__ bf16x8 as_bf16x8(us8 v) {
    return __builtin_bit_cast(bf16x8, v);
}
__device__ __forceinline__ float bfl(unsigned short u) {
    return __builtin_bit_cast(float, ((unsigned)u) << 16);
}

// per-wave transpose buffer: 16 rows x 64 cols bf16, XOR-swizzled
__device__ __forceinline__ int tb_off(int m, int j) {
    return m * 64 + ((((j * 2) ^ ((m & 7) << 4))) >> 1);
}
__device__ __forceinline__ bf16x8 ld_tb(const unsigned short* tb, int m, int j0) {
    return as_bf16x8(*(const us8*)&tb[tb_off(m, j0)]);
}
// weight B-fragment from global (L1/L2-hot, 40KB working set per pass)
__device__ __forceinline__ bf16x8 ld_frg(const ushort_t* __restrict__ FRG, int fid, int lane) {
    return as_bf16x8(*(const us8*)&FRG[(fid * 64 + lane) * 8]);
}

// ---------------- one-time weight fragment pre-pack --------------------------
// frag ids per set: [0,16)=W1(s=fid>>2,t=fid&3), [16,24)=W2, [24,40)=W3
// set 0 = inv weights, set 1 = and weights. 80 frags x 64 lanes x 8 bf16.
__global__ __launch_bounds__(256) void prep_frags_k(
    const float* __restrict__ iw1, const float* __restrict__ iw2,
    const float* __restrict__ iw3,
    const float* __restrict__ aw1, const float* __restrict__ aw2,
    const float* __restrict__ aw3,
    ushort_t* __restrict__ frg)
{
    const int g = blockIdx.x * 256 + threadIdx.x;   // 80*64 = 5120 threads
    const int fid2 = g >> 6;
    if (fid2 >= 80) return;
    const int lane = g & 63;
    const int ln = lane & 15, hi = lane >> 4;
    const int set = fid2 / 40;
    const int fid = fid2 - set * 40;
    const float* w; int inF, s, t;
    if (fid < 16)      { w = set ? aw1 : iw1; inF = H;  s = fid >> 2;        t = fid & 3; }
    else if (fid < 24) { w = set ? aw2 : iw2; inF = HH; s = (fid - 16) >> 2; t = (fid - 16) & 3; }
    else               { w = set ? aw3 : iw3; inF = HH; s = (fid - 24) >> 3; t = (fid - 24) & 7; }
    const float* p = w + (size_t)(t * 16 + ln) * inF + (s * 32 + hi * 8);
    f32x4 a = *(const f32x4*)p;
    f32x4 b = *(const f32x4*)(p + 4);
    ushort_t* d = &frg[(size_t)(fid2 * 64 + lane) * 8];
    d[0] = bfbits(a[0]); d[1] = bfbits(a[1]); d[2] = bfbits(a[2]); d[3] = bfbits(a[3]);
    d[4] = bfbits(b[0]); d[5] = bfbits(b[1]); d[6] = bfbits(b[2]); d[7] = bfbits(b[3]);
}

// ---------------- fused 3-layer MLP, persistent blocks, barrier-free ---------
// INB:   X is bf16 row-major, else f32
// OUTB:  OUT is bf16 (staged through LDS, coalesced)
// WF:    also write bf16 copy of X to xtra (requires !INB)
// LIST:  input row = pos (compact), output row = rows[pos], count rowcnt[0]
// SPLIT: out rows with invp==0 -> f32 OUT; invp==1 -> bf16 xtra[irank[row]]
template<bool INB, bool OUTB, bool WF, bool LIST, bool SPLIT>
__global__ __launch_bounds__(512, 6) void mlp3_t(
    const void* X_,
    const ushort_t* __restrict__ FRG,
    const float* __restrict__ B1, const float* __restrict__ B2,
    const float* __restrict__ B3,
    void* OUT_,
    ushort_t* __restrict__ xtra,
    const int* __restrict__ rows, const int* __restrict__ rowcnt,
    const int* __restrict__ invp, const int* __restrict__ irank,
    int nrows, int ntiles)
{
    __shared__ __align__(16) unsigned short TBs[NW * 16 * 64];  // 16 KB only
    const float*    Xf = (const float*)X_;
    const ushort_t* Xb = (const ushort_t*)X_;

    const int tid  = threadIdx.x;
    const int wv   = tid >> 6;
    const int lane = tid & 63;
    const int ln   = lane & 15;
    const int hi   = lane >> 4;

    float b1r[4], b2r[4], b3r[8];
#pragma unroll
    for (int t = 0; t < 4; ++t) b1r[t] = B1[t * 16 + ln];
#pragma unroll
    for (int t = 0; t < 4; ++t) b2r[t] = B2[t * 16 + ln];
#pragma unroll
    for (int t = 0; t < 8; ++t) b3r[t] = B3[t * 16 + ln];

    int rcnt, tcount;
    if constexpr (LIST) { rcnt = rowcnt[0]; tcount = (rcnt + 15) >> 4; }
    else                { rcnt = nrows;     tcount = ntiles; }

    unsigned short* tb = &TBs[wv * 16 * 64];

    for (int tile = blockIdx.x * NW + wv; tile < tcount; tile += gridDim.x * NW) {
        const int node0 = tile * 16;
        const int lpos  = min(node0 + ln, rcnt - 1);
        const size_t ro = (size_t)lpos * H;

        bf16x8 a1[4];
#pragma unroll
        for (int s = 0; s < 4; ++s) {
            if constexpr (INB) {
                a1[s] = as_bf16x8(*(const us8*)(Xb + ro + s * 32 + hi * 8));
            } else {
                f32x4 u = *(const f32x4*)(Xf + ro + s * 32 + hi * 8);
                f32x4 v = *(const f32x4*)(Xf + ro + s * 32 + hi * 8 + 4);
                bf16x8 f;
                f[0] = (__bf16)u[0]; f[1] = (__bf16)u[1]; f[2] = (__bf16)u[2]; f[3] = (__bf16)u[3];
                f[4] = (__bf16)v[0]; f[5] = (__bf16)v[1]; f[6] = (__bf16)v[2]; f[7] = (__bf16)v[3];
                a1[s] = f;
                if constexpr (WF)
                    *(us8*)(xtra + ro + s * 32 + hi * 8) = __builtin_bit_cast(us8, f);
            }
        }

        // layer 1
#pragma unroll
        for (int t = 0; t < 4; ++t) {
            f32x4 acc = {0.f, 0.f, 0.f, 0.f};
#pragma unroll
            for (int s = 0; s < 4; ++s)
                acc = __builtin_amdgcn_mfma_f32_16x16x32_bf16(a1[s], ld_frg(FRG, s * 4 + t, lane), acc, 0, 0, 0);
#pragma unroll
            for (int q = 0; q < 4; ++q) {
                float y = acc[q] + b1r[t];
                y = (y >= 0.f) ? y : 0.01f * y;
                tb[tb_off(hi * 4 + q, t * 16 + ln)] = bfbits(y);
            }
        }

        // layer 2
        bf16x8 a2[2];
#pragma unroll
        for (int s = 0; s < 2; ++s) a2[s] = ld_tb(tb, ln, s * 32 + hi * 8);
#pragma unroll
        for (int t = 0; t < 4; ++t) {
            f32x4 acc = {0.f, 0.f, 0.f, 0.f};
#pragma unroll
            for (int s = 0; s < 2; ++s)
                acc = __builtin_amdgcn_mfma_f32_16x16x32_bf16(a2[s], ld_frg(FRG, 16 + s * 4 + t, lane), acc, 0, 0, 0);
#pragma unroll
            for (int q = 0; q < 4; ++q) {
                float y = acc[q] + b2r[t];
                y = (y >= 0.f) ? y : 0.01f * y;
                tb[tb_off(hi * 4 + q, t * 16 + ln)] = bfbits(y);
            }
        }

        // layer 3
        bf16x8 a3[2];
#pragma unroll
        for (int s = 0; s < 2; ++s) a3[s] = ld_tb(tb, ln, s * 32 + hi * 8);

        if constexpr (OUTB) {
            ushort_t* OUTb = (ushort_t*)OUT_;
#pragma unroll
            for (int half = 0; half < 2; ++half) {
#pragma unroll
                for (int t2 = 0; t2 < 4; ++t2) {
                    const int t = half * 4 + t2;
                    f32x4 acc = {0.f, 0.f, 0.f, 0.f};
#pragma unroll
                    for (int s = 0; s < 2; ++s)
                        acc = __builtin_amdgcn_mfma_f32_16x16x32_bf16(a3[s], ld_frg(FRG, 24 + s * 8 + t, lane), acc, 0, 0, 0);
#pragma unroll
                    for (int q = 0; q < 4; ++q)
                        tb[tb_off(hi * 4 + q, t2 * 16 + ln)] = bfbits(acc[q] + b3r[t]);
                }
                const int rr = lane >> 2, c0 = (lane & 3) * 16;
                if (node0 + rr < rcnt) {
                    us8 w0 = __builtin_bit_cast(us8, ld_tb(tb, rr, c0));
                    us8 w1 = __builtin_bit_cast(us8, ld_tb(tb, rr, c0 + 8));
                    ushort_t* op = OUTb + (size_t)(node0 + rr) * H + half * 64 + c0;
                    *(us8*)op = w0;
                    *(us8*)(op + 8) = w1;
                }
            }
        } else if constexpr (SPLIT) {
            float* OUTf = (float*)OUT_;
            int iq[4];
#pragma unroll
            for (int q = 0; q < 4; ++q) {
                const int row = node0 + hi * 4 + q;
                iq[q] = (row < rcnt) ? invp[row] : 1;
            }
            const int rr = lane >> 2, c0 = (lane & 3) * 16;
            const int rowrr = node0 + rr;
            const bool winv = (rowrr < rcnt) && (invp[rowrr] != 0);
            const int irk = winv ? irank[rowrr] : 0;
#pragma unroll
            for (int half = 0; half < 2; ++half) {
#pragma unroll
                for (int t2 = 0; t2 < 4; ++t2) {
                    const int t = half * 4 + t2;
                    f32x4 acc = {0.f, 0.f, 0.f, 0.f};
#pragma unroll
                    for (int s = 0; s < 2; ++s)
                        acc = __builtin_amdgcn_mfma_f32_16x16x32_bf16(a3[s], ld_frg(FRG, 24 + s * 8 + t, lane), acc, 0, 0, 0);
#pragma unroll
                    for (int q = 0; q < 4; ++q) {
                        const float y = acc[q] + b3r[t];
                        tb[tb_off(hi * 4 + q, t2 * 16 + ln)] = bfbits(y);
                        const int row = node0 + hi * 4 + q;
                        if (row < rcnt && !iq[q])
                            OUTf[(size_t)row * H + half * 64 + t2 * 16 + ln] = y;
                    }
                }
                if (winv) {
                    us8 w0 = __builtin_bit_cast(us8, ld_tb(tb, rr, c0));
                    us8 w1 = __builtin_bit_cast(us8, ld_tb(tb, rr, c0 + 8));
                    ushort_t* op = xtra + (size_t)irk * H + half * 64 + c0;
                    *(us8*)op = w0;
                    *(us8*)(op + 8) = w1;
                }
            }
        } else {
            float* OUTf = (float*)OUT_;
            int grow[4];
#pragma unroll
            for (int q = 0; q < 4; ++q) {
                const int pos = node0 + hi * 4 + q;
                grow[q] = (pos < rcnt) ? (LIST ? rows[pos] : pos) : -1;
            }
#pragma unroll
            for (int t = 0; t < 8; ++t) {
                f32x4 acc = {0.f, 0.f, 0.f, 0.f};
#pragma unroll
                for (int s = 0; s < 2; ++s)
                    acc = __builtin_amdgcn_mfma_f32_16x16x32_bf16(a3[s], ld_frg(FRG, 24 + s * 8 + t, lane), acc, 0, 0, 0);
#pragma unroll
                for (int q = 0; q < 4; ++q) {
                    if (grow[q] >= 0)
                        OUTf[(size_t)grow[q] * H + t * 16 + ln] = acc[q] + b3r[t];
                }
            }
        }
    }
}

// ---------------- CSR build (two-level counting sort) + fused inv scan -------
// blocks [0,cgrid): coarse histogram of dst>>BSH. blocks [cgrid,+nchunks): iscan1.
__global__ __launch_bounds__(256) void coarse_hist_k(
    const int* __restrict__ dst, int* __restrict__ chist,
    const int* __restrict__ inv, int* __restrict__ bsumI,
    int E, int N, int cgrid)
{
    __shared__ int h[256];
    const int tid = threadIdx.x;
    if (blockIdx.x < cgrid) {
        h[tid] = 0;
        __syncthreads();
        const int base = blockIdx.x * ACH;
#pragma unroll
        for (int j = 0; j < 8; ++j) {
            const int e = base + j * 256 + tid;
            if (e < E) atomicAdd(&h[dst[e] >> BSH], 1);
        }
        __syncthreads();
        if (h[tid]) atomicAdd(&chist[tid], h[tid]);
    } else {
        const int b = blockIdx.x - cgrid;
        const int base = b * CHUNK + tid * 8;
        int sumi = 0;
#pragma unroll
        for (int j = 0; j < 8; ++j) { int i = base + j; if (i < N) sumi += inv[i]; }
        h[tid] = sumi;
        __syncthreads();
        for (int st = 128; st > 0; st >>= 1) {
            if (tid < st) h[tid] += h[tid + st];
            __syncthreads();
        }
        if (tid == 0) bsumI[b] = h[0];
    }
}

// single block: coarse-bucket scan (cbase/ccur) + inv chunk scan (bsumI, icnt)
__global__ __launch_bounds__(256) void cscan_k(
    const int* __restrict__ chist, int* __restrict__ cbase, int* __restrict__ ccur,
    int* __restrict__ bsumI, int* __restrict__ icnt,
    int nb, int E, int nchunks)
{
    __shared__ int s[256];
    const int tid = threadIdx.x;
    const int v = (tid < nb) ? chist[tid] : 0;
    s[tid] = v;
    __syncthreads();
    for (int st = 1; st < 256; st <<= 1) {
        int t = (tid >= st) ? s[tid - st] : 0;
        __syncthreads();
        s[tid] += t;
        __syncthreads();
    }
    const int excl = s[tid] - v;
    if (tid < nb) { cbase[tid] = excl; ccur[tid] = excl; }
    if (tid == 0) cbase[nb] = E;
    __syncthreads();
    const int u0 = (tid < nchunks) ? bsumI[tid] : 0;
    s[tid] = u0;
    __syncthreads();
    for (int st = 1; st < 256; st <<= 1) {
        int t = (tid >= st) ? s[tid - st] : 0;
        __syncthreads();
        s[tid] += t;
        __syncthreads();
    }
    if (tid < nchunks) bsumI[tid] = s[tid] - u0;
    if (tid == 255) icnt[0] = s[255];
}

// blocks [0,cgrid): coarse bin pass. blocks [cgrid,+nchunks): iscan3 (ilist/irank)
__global__ __launch_bounds__(256) void coarse_bin_k(
    const int* __restrict__ src, const int* __restrict__ dst,
    const int* __restrict__ r,
    int* __restrict__ ccur, unsigned* __restrict__ ebuf,
    const int* __restrict__ inv, const int* __restrict__ bsumI,
    int* __restrict__ ilist, int* __restrict__ irank,
    int E, int N, int cgrid)
{
    __shared__ int hcnt[256];
    __shared__ int gbase[256];
    __shared__ int lcur[256];
    const int tid = threadIdx.x;
    if (blockIdx.x < cgrid) {
        hcnt[tid] = 0;
        __syncthreads();
        const int base = blockIdx.x * ACH;
        unsigned v[8]; int bk[8];
#pragma unroll
        for (int j = 0; j < 8; ++j) {
            const int e = base + j * 256 + tid;
            if (e < E) {
                const int d = dst[e];
                bk[j] = d >> BSH;
                v[j] = ((unsigned)(d & (BSZ - 1)) << 18) |
                       ((unsigned)src[e] << 1) | (unsigned)r[e];
                atomicAdd(&hcnt[bk[j]], 1);
            } else bk[j] = -1;
        }
        __syncthreads();
        const int c = hcnt[tid];
        gbase[tid] = (c > 0) ? atomicAdd(&ccur[tid], c) : 0;
        lcur[tid] = 0;
        __syncthreads();
#pragma unroll
        for (int j = 0; j < 8; ++j) {
            if (bk[j] >= 0) {
                const int loc = atomicAdd(&lcur[bk[j]], 1);
                ebuf[gbase[bk[j]] + loc] = v[j];
            }
        }
    } else {
        const int b = blockIdx.x - cgrid;
        const int base = b * CHUNK + tid * 8;
        int vi[8]; int tsumi = 0;
#pragma unroll
        for (int j = 0; j < 8; ++j) {
            int t = (base + j < N) ? inv[base + j] : 0;
            vi[j] = tsumi; tsumi += t;
        }
        hcnt[tid] = tsumi;
        __syncthreads();
        for (int st = 1; st < 256; st <<= 1) {
            int val = (tid >= st) ? hcnt[tid - st] : 0;
            __syncthreads();
            hcnt[tid] += val;
            __syncthreads();
        }
        const int texclI = hcnt[tid] - tsumi + bsumI[b];
#pragma unroll
        for (int j = 0; j < 8; ++j) {
            int i = base + j;
            if (i < N && inv[i]) {
                const int rank = texclI + vi[j];
                ilist[rank] = i;
                irank[i] = rank;
            }
        }
    }
}

// fine pass: one block per 512-node bucket. LDS hist + LDS scan emit offsets;
// LDS cursors scatter packed. Output region ~16KB stays in one XCD L2.
__global__ __launch_bounds__(512) void fine_build_k(
    const unsigned* __restrict__ ebuf, const int* __restrict__ cbase,
    int* __restrict__ offsets, int* __restrict__ packed, int N, int E, int nb)
{
    __shared__ int loff[BSZ];
    __shared__ int lcur[BSZ];
    const int b = blockIdx.x, tid = threadIdx.x;
    const int lo = b << BSH;
    const int nn = min(BSZ, N - lo);
    const int rstart = cbase[b];
    const int rend   = cbase[b + 1];
    lcur[tid] = 0;
    __syncthreads();
    for (int i = rstart + tid; i < rend; i += BSZ)
        atomicAdd(&lcur[ebuf[i] >> 18], 1);
    __syncthreads();
    const int v = lcur[tid];
    loff[tid] = v;
    __syncthreads();
    for (int st = 1; st < BSZ; st <<= 1) {
        int t = (tid >= st) ? loff[tid - st] : 0;
        __syncthreads();
        loff[tid] += t;
        __syncthreads();
    }
    const int base = rstart + loff[tid] - v;     // exclusive prefix
    if (tid < nn) offsets[lo + tid] = base;
    if (b == nb - 1 && tid == 0) offsets[N] = E;
    __syncthreads();
    lcur[tid] = base;
    __syncthreads();
    for (int i = rstart + tid; i < rend; i += BSZ) {
        const unsigned w = ebuf[i];
        const int dloc = w >> 18;
        const int pos = atomicAdd(&lcur[dloc], 1);
        packed[pos] = (int)(((w & 0x3ffffu) >> 1) | ((w & 1u) << 31));
    }
}

// one wave per node: 4 rows x 16 lanes x 16B, 16 rows in flight; f32 accum;
// shfl_xor(16,32) combine; bf16 mean out. deg = offsets diff.
__global__ __launch_bounds__(256) void gather_mean_k(
    const ushort_t* __restrict__ featb, const ushort_t* __restrict__ invb,
    const int* __restrict__ offsets,
    const int* __restrict__ packed, ushort_t* __restrict__ neighb, int N)
{
    const int wv = threadIdx.x >> 6, lane = threadIdx.x & 63;
    const int n = blockIdx.x * 4 + wv;
    if (n >= N) return;
    const int start = offsets[n];
    const int d = offsets[n + 1] - start;
    const int q4 = lane >> 4;                    // row-in-group 0..3
    const size_t co = (size_t)(lane & 15) * 8;   // col base
    float a[8] = {0.f, 0.f, 0.f, 0.f, 0.f, 0.f, 0.f, 0.f};
    int k = 0;
    for (; k + 15 < d; k += 16) {
        const int p0 = packed[start + k + q4];
        const int p1 = packed[start + k + 4 + q4];
        const int p2 = packed[start + k + 8 + q4];
        const int p3 = packed[start + k + 12 + q4];
        const ushort_t* t0 = (p0 < 0) ? invb : featb;
        const ushort_t* t1 = (p1 < 0) ? invb : featb;
        const ushort_t* t2 = (p2 < 0) ? invb : featb;
        const ushort_t* t3 = (p3 < 0) ? invb : featb;
        const us8 u0 = *(const us8*)(t0 + (size_t)(p0 & 0x7fffffff) * H + co);
        const us8 u1 = *(const us8*)(t1 + (size_t)(p1 & 0x7fffffff) * H + co);
        const us8 u2 = *(const us8*)(t2 + (size_t)(p2 & 0x7fffffff) * H + co);
        const us8 u3 = *(const us8*)(t3 + (size_t)(p3 & 0x7fffffff) * H + co);
#pragma unroll
        for (int i = 0; i < 8; ++i) a[i] += (bfl(u0[i]) + bfl(u1[i])) + (bfl(u2[i]) + bfl(u3[i]));
    }
    for (; k + 7 < d; k += 8) {
        const int pA = packed[start + k + q4];
        const int pB = packed[start + k + 4 + q4];
        const ushort_t* tA = (pA < 0) ? invb : featb;
        const ushort_t* tB = (pB < 0) ? invb : featb;
        const us8 uA = *(const us8*)(tA + (size_t)(pA & 0x7fffffff) * H + co);
        const us8 uB = *(const us8*)(tB + (size_t)(pB & 0x7fffffff) * H + co);
#pragma unroll
        for (int i = 0; i < 8; ++i) a[i] += bfl(uA[i]) + bfl(uB[i]);
    }
    if (k + 3 < d) {
        const int p = packed[start + k + q4];
        const ushort_t* t = (p < 0) ? invb : featb;
        const us8 u = *(const us8*)(t + (size_t)(p & 0x7fffffff) * H + co);
#pragma unroll
        for (int i = 0; i < 8; ++i) a[i] += bfl(u[i]);
        k += 4;
    }
    const int rem = d - k;
    if (q4 < rem) {
        const int p = packed[start + k + q4];
        const ushort_t* t = (p < 0) ? invb : featb;
        const us8 u = *(const us8*)(t + (size_t)(p & 0x7fffffff) * H + co);
#pragma unroll
        for (int i = 0; i < 8; ++i) a[i] += bfl(u[i]);
    }
#pragma unroll
    for (int i = 0; i < 8; ++i) {
        a[i] += __shfl_xor(a[i], 16);
        a[i] += __shfl_xor(a[i], 32);
    }
    if (q4 == 0) {
        const float scl = 1.0f / (float)max(d, 1);
        us8 o;
#pragma unroll
        for (int i = 0; i < 8; ++i) o[i] = bfbits(a[i] * scl);
        *(us8*)(neighb + (size_t)n * H + co) = o;
    }
}

extern "C" void kernel_launch(void* const* d_in, const int* in_sizes, int n_in,
                              void* d_out, int out_size, void* d_ws, size_t ws_size,
                              hipStream_t stream) {
    const float* feat = (const float*)d_in[0];
    const int*   src  = (const int*)d_in[1];
    const int*   dst  = (const int*)d_in[2];
    const int*   r    = (const int*)d_in[3];
    const int*   inv  = (const int*)d_in[4];
    const float* iw1 = (const float*)d_in[5],  *ib1 = (const float*)d_in[6];
    const float* iw2 = (const float*)d_in[7],  *ib2 = (const float*)d_in[8];
    const float* iw3 = (const float*)d_in[9],  *ib3 = (const float*)d_in[10];
    const float* aw1 = (const float*)d_in[11], *ab1 = (const float*)d_in[12];
    const float* aw2 = (const float*)d_in[13], *ab2 = (const float*)d_in[14];
    const float* aw3 = (const float*)d_in[15], *ab3 = (const float*)d_in[16];

    const int N = in_sizes[4];   // inv is [N]
    const int E = in_sizes[1];   // src is [E]

    ushort_t* featb  = (ushort_t*)d_ws;             // N*H bf16; dead after gather
    ushort_t* resb   = featb;                       //   ...aliased by resb (pass4/5)
    ushort_t* invb   = featb + (size_t)N * H;       // N*H bf16
    ushort_t* neighb = invb + (size_t)N * H;        // N*H bf16
    int* offsets = (int*)(neighb + (size_t)N * H);  // N+1
    int* ilist   = offsets + (N + 1);
    int* irank   = ilist + N;
    unsigned* ebuf = (unsigned*)(irank + N);
    int* packed  = (int*)(ebuf + E);
    ushort_t* frg = (ushort_t*)(packed + E);        // 80 frags x 512 us = 80 KB
    int* chist   = (int*)(frg + 80 * 512);
    int* cbase   = chist + 256;                     // 257
    int* ccur    = cbase + 257;
    int* bsumI   = ccur + 256;
    int* icnt    = bsumI + 256;

    ushort_t* frg_inv = frg;
    ushort_t* frg_and = frg + 40 * 512;

    const int nchunks = (N + CHUNK - 1) / CHUNK;
    const int ntiles  = (N + 15) / 16;
    const int NB      = (N + BSZ - 1) / BSZ;        // coarse buckets (<=256)
    const int cgrid   = (E + ACH - 1) / ACH;
    const int g1      = min((ntiles + NW - 1) / NW, 768);  // 3 blocks/CU

    hipMemsetAsync(chist, 0, 256 * sizeof(int), stream);

    // 0) pre-pack weight B-fragments (both sets) into global frag table
    prep_frags_k<<<20, 256, 0, stream>>>(iw1, iw2, iw3, aw1, aw2, aw3, frg);
    // 1) invb = bf16(mlp_inv(feat)); featb = bf16(feat)
    mlp3_t<false, true, true, false, false><<<g1, 512, 0, stream>>>(
        feat, frg_inv, ib1, ib2, ib3, invb, featb,
        nullptr, nullptr, nullptr, nullptr, N, ntiles);
    // 2) CSR build: coarse hist (+iscan1) -> scan (+iscan2) -> bin (+iscan3) -> fine
    coarse_hist_k<<<cgrid + nchunks, 256, 0, stream>>>(dst, chist, inv, bsumI, E, N, cgrid);
    cscan_k<<<1, 256, 0, stream>>>(chist, cbase, ccur, bsumI, icnt, NB, E, nchunks);
    coarse_bin_k<<<cgrid + nchunks, 256, 0, stream>>>(src, dst, r, ccur, ebuf,
                                                      inv, bsumI, ilist, irank, E, N, cgrid);
    fine_build_k<<<NB, BSZ, 0, stream>>>(ebuf, cbase, offsets, packed, N, E, NB);
    // 3) neighb = bf16(mean of messages)
    gather_mean_k<<<(N + 3) / 4, 256, 0, stream>>>(featb, invb, offsets,
                                                   packed, neighb, N);
    // 4) res = mlp_and(neighb): non-inv rows f32 -> d_out, inv rows bf16 -> resb
    mlp3_t<true, false, false, false, true><<<g1, 512, 0, stream>>>(
        neighb, frg_and, ab1, ab2, ab3, d_out, resb,
        nullptr, nullptr, inv, irank, N, ntiles);
    // 5) d_out[ilist] = mlp_inv(resb)  (compact bf16 in, scattered f32 out)
    mlp3_t<true, false, false, true, false><<<g1, 512, 0, stream>>>(
        resb, frg_inv, ib1, ib2, ib3, d_out, nullptr,
        ilist, icnt, nullptr, nullptr, N, ntiles);
}

// Round 8
// 163.353 us; speedup vs baseline: 2.7230x; 2.7230x over previous
//
#include <hip/hip_runtime.h>

// FuncConv: out = select(inv, mlp_inv(res), res); res = mlp_and(mean_dst(msg));
// msg = select(r, mlp_inv(feat[src]), feat[src]).
// R7: R6 regressed 165->445us from scratch spill (uniform +236MB WRITE on all
// mlp passes, VGPR 52->40, all pipes idle): launch_bounds(512,6) capped VGPRs
// at ~85 while unrolled global frag loads raised demand. Fix: (a) drop the
// min-waves cap; (b) #pragma unroll 2 on MFMA t-loops to bound the number of
// in-flight frag-load live ranges; (c) one tile per wave grid.
//
// ws: featb[N*H bf16 | resb aliases] invb[N*H bf16] neighb[N*H bf16]
//     offsets[N+1] ilist[N] irank[N] ebuf[E] packed[E]
//     frg[80*512 us] chist[256] cbase[257] ccur[256] bsumI[256] icnt[1]

#define H 128
#define HH 64
#define CHUNK 2048
#define NW 8      // waves per MLP block
#define BSH 9     // log2 nodes per coarse bucket
#define BSZ 512   // nodes per coarse bucket
#define ACH 2048  // edges per coarse block

typedef float f32x4 __attribute__((ext_vector_type(4)));
typedef __bf16 bf16x8 __attribute__((ext_vector_type(8)));
typedef unsigned short us8 __attribute__((ext_vector_type(8)));
typedef unsigned short ushort_t;

__device__ __forceinline__ unsigned short bfbits(float f) {
    __bf16 h = (__bf16)f;                       // RNE convert
    return __builtin_bit_cast(unsigned short, h);
}
__device__ __forceinline__ bf16x8 as_bf16x8(us8 v) {
    return __builtin_bit_cast(bf16x8, v);
}
__device__ __forceinline__ float bfl(unsigned short u) {
    return __builtin_bit_cast(float, ((unsigned)u) << 16);
}

// per-wave transpose buffer: 16 rows x 64 cols bf16, XOR-swizzled
__device__ __forceinline__ int tb_off(int m, int j) {
    return m * 64 + ((((j * 2) ^ ((m & 7) << 4))) >> 1);
}
__device__ __forceinline__ bf16x8 ld_tb(const unsigned short* tb, int m, int j0) {
    return as_bf16x8(*(const us8*)&tb[tb_off(m, j0)]);
}
// weight B-fragment from global (L1/L2-hot, 40KB working set per pass)
__device__ __forceinline__ bf16x8 ld_frg(const ushort_t* __restrict__ FRG, int fid, int lane) {
    return as_bf16x8(*(const us8*)&FRG[(fid * 64 + lane) * 8]);
}

// ---------------- one-time weight fragment pre-pack --------------------------
// frag ids per set: [0,16)=W1(s=fid>>2,t=fid&3), [16,24)=W2, [24,40)=W3
// set 0 = inv weights, set 1 = and weights. 80 frags x 64 lanes x 8 bf16.
__global__ __launch_bounds__(256) void prep_frags_k(
    const float* __restrict__ iw1, const float* __restrict__ iw2,
    const float* __restrict__ iw3,
    const float* __restrict__ aw1, const float* __restrict__ aw2,
    const float* __restrict__ aw3,
    ushort_t* __restrict__ frg)
{
    const int g = blockIdx.x * 256 + threadIdx.x;   // 80*64 = 5120 threads
    const int fid2 = g >> 6;
    if (fid2 >= 80) return;
    const int lane = g & 63;
    const int ln = lane & 15, hi = lane >> 4;
    const int set = fid2 / 40;
    const int fid = fid2 - set * 40;
    const float* w; int inF, s, t;
    if (fid < 16)      { w = set ? aw1 : iw1; inF = H;  s = fid >> 2;        t = fid & 3; }
    else if (fid < 24) { w = set ? aw2 : iw2; inF = HH; s = (fid - 16) >> 2; t = (fid - 16) & 3; }
    else               { w = set ? aw3 : iw3; inF = HH; s = (fid - 24) >> 3; t = (fid - 24) & 7; }
    const float* p = w + (size_t)(t * 16 + ln) * inF + (s * 32 + hi * 8);
    f32x4 a = *(const f32x4*)p;
    f32x4 b = *(const f32x4*)(p + 4);
    ushort_t* d = &frg[(size_t)(fid2 * 64 + lane) * 8];
    d[0] = bfbits(a[0]); d[1] = bfbits(a[1]); d[2] = bfbits(a[2]); d[3] = bfbits(a[3]);
    d[4] = bfbits(b[0]); d[5] = bfbits(b[1]); d[6] = bfbits(b[2]); d[7] = bfbits(b[3]);
}

// ---------------- fused 3-layer MLP, persistent blocks, barrier-free ---------
// INB:   X is bf16 row-major, else f32
// OUTB:  OUT is bf16 (staged through LDS, coalesced)
// WF:    also write bf16 copy of X to xtra (requires !INB)
// LIST:  input row = pos (compact), output row = rows[pos], count rowcnt[0]
// SPLIT: out rows with invp==0 -> f32 OUT; invp==1 -> bf16 xtra[irank[row]]
template<bool INB, bool OUTB, bool WF, bool LIST, bool SPLIT>
__global__ __launch_bounds__(512) void mlp3_t(
    const void* X_,
    const ushort_t* __restrict__ FRG,
    const float* __restrict__ B1, const float* __restrict__ B2,
    const float* __restrict__ B3,
    void* OUT_,
    ushort_t* __restrict__ xtra,
    const int* __restrict__ rows, const int* __restrict__ rowcnt,
    const int* __restrict__ invp, const int* __restrict__ irank,
    int nrows, int ntiles)
{
    __shared__ __align__(16) unsigned short TBs[NW * 16 * 64];  // 16 KB only
    const float*    Xf = (const float*)X_;
    const ushort_t* Xb = (const ushort_t*)X_;

    const int tid  = threadIdx.x;
    const int wv   = tid >> 6;
    const int lane = tid & 63;
    const int ln   = lane & 15;
    const int hi   = lane >> 4;

    float b1r[4], b2r[4], b3r[8];
#pragma unroll
    for (int t = 0; t < 4; ++t) b1r[t] = B1[t * 16 + ln];
#pragma unroll
    for (int t = 0; t < 4; ++t) b2r[t] = B2[t * 16 + ln];
#pragma unroll
    for (int t = 0; t < 8; ++t) b3r[t] = B3[t * 16 + ln];

    int rcnt, tcount;
    if constexpr (LIST) { rcnt = rowcnt[0]; tcount = (rcnt + 15) >> 4; }
    else                { rcnt = nrows;     tcount = ntiles; }

    unsigned short* tb = &TBs[wv * 16 * 64];

    for (int tile = blockIdx.x * NW + wv; tile < tcount; tile += gridDim.x * NW) {
        const int node0 = tile * 16;
        const int lpos  = min(node0 + ln, rcnt - 1);
        const size_t ro = (size_t)lpos * H;

        bf16x8 a1[4];
#pragma unroll
        for (int s = 0; s < 4; ++s) {
            if constexpr (INB) {
                a1[s] = as_bf16x8(*(const us8*)(Xb + ro + s * 32 + hi * 8));
            } else {
                f32x4 u = *(const f32x4*)(Xf + ro + s * 32 + hi * 8);
                f32x4 v = *(const f32x4*)(Xf + ro + s * 32 + hi * 8 + 4);
                bf16x8 f;
                f[0] = (__bf16)u[0]; f[1] = (__bf16)u[1]; f[2] = (__bf16)u[2]; f[3] = (__bf16)u[3];
                f[4] = (__bf16)v[0]; f[5] = (__bf16)v[1]; f[6] = (__bf16)v[2]; f[7] = (__bf16)v[3];
                a1[s] = f;
                if constexpr (WF)
                    *(us8*)(xtra + ro + s * 32 + hi * 8) = __builtin_bit_cast(us8, f);
            }
        }

        // layer 1  (unroll 2: bound concurrent frag-load live ranges)
#pragma unroll 2
        for (int t = 0; t < 4; ++t) {
            f32x4 acc = {0.f, 0.f, 0.f, 0.f};
#pragma unroll
            for (int s = 0; s < 4; ++s)
                acc = __builtin_amdgcn_mfma_f32_16x16x32_bf16(a1[s], ld_frg(FRG, s * 4 + t, lane), acc, 0, 0, 0);
#pragma unroll
            for (int q = 0; q < 4; ++q) {
                float y = acc[q] + b1r[t];
                y = (y >= 0.f) ? y : 0.01f * y;
                tb[tb_off(hi * 4 + q, t * 16 + ln)] = bfbits(y);
            }
        }

        // layer 2
        bf16x8 a2[2];
#pragma unroll
        for (int s = 0; s < 2; ++s) a2[s] = ld_tb(tb, ln, s * 32 + hi * 8);
#pragma unroll 2
        for (int t = 0; t < 4; ++t) {
            f32x4 acc = {0.f, 0.f, 0.f, 0.f};
#pragma unroll
            for (int s = 0; s < 2; ++s)
                acc = __builtin_amdgcn_mfma_f32_16x16x32_bf16(a2[s], ld_frg(FRG, 16 + s * 4 + t, lane), acc, 0, 0, 0);
#pragma unroll
            for (int q = 0; q < 4; ++q) {
                float y = acc[q] + b2r[t];
                y = (y >= 0.f) ? y : 0.01f * y;
                tb[tb_off(hi * 4 + q, t * 16 + ln)] = bfbits(y);
            }
        }

        // layer 3
        bf16x8 a3[2];
#pragma unroll
        for (int s = 0; s < 2; ++s) a3[s] = ld_tb(tb, ln, s * 32 + hi * 8);

        if constexpr (OUTB) {
            ushort_t* OUTb = (ushort_t*)OUT_;
#pragma unroll
            for (int half = 0; half < 2; ++half) {
#pragma unroll 2
                for (int t2 = 0; t2 < 4; ++t2) {
                    const int t = half * 4 + t2;
                    f32x4 acc = {0.f, 0.f, 0.f, 0.f};
#pragma unroll
                    for (int s = 0; s < 2; ++s)
                        acc = __builtin_amdgcn_mfma_f32_16x16x32_bf16(a3[s], ld_frg(FRG, 24 + s * 8 + t, lane), acc, 0, 0, 0);
#pragma unroll
                    for (int q = 0; q < 4; ++q)
                        tb[tb_off(hi * 4 + q, t2 * 16 + ln)] = bfbits(acc[q] + b3r[t]);
                }
                const int rr = lane >> 2, c0 = (lane & 3) * 16;
                if (node0 + rr < rcnt) {
                    us8 w0 = __builtin_bit_cast(us8, ld_tb(tb, rr, c0));
                    us8 w1 = __builtin_bit_cast(us8, ld_tb(tb, rr, c0 + 8));
                    ushort_t* op = OUTb + (size_t)(node0 + rr) * H + half * 64 + c0;
                    *(us8*)op = w0;
                    *(us8*)(op + 8) = w1;
                }
            }
        } else if constexpr (SPLIT) {
            float* OUTf = (float*)OUT_;
            int iq[4];
#pragma unroll
            for (int q = 0; q < 4; ++q) {
                const int row = node0 + hi * 4 + q;
                iq[q] = (row < rcnt) ? invp[row] : 1;
            }
            const int rr = lane >> 2, c0 = (lane & 3) * 16;
            const int rowrr = node0 + rr;
            const bool winv = (rowrr < rcnt) && (invp[rowrr] != 0);
            const int irk = winv ? irank[rowrr] : 0;
#pragma unroll
            for (int half = 0; half < 2; ++half) {
#pragma unroll 2
                for (int t2 = 0; t2 < 4; ++t2) {
                    const int t = half * 4 + t2;
                    f32x4 acc = {0.f, 0.f, 0.f, 0.f};
#pragma unroll
                    for (int s = 0; s < 2; ++s)
                        acc = __builtin_amdgcn_mfma_f32_16x16x32_bf16(a3[s], ld_frg(FRG, 24 + s * 8 + t, lane), acc, 0, 0, 0);
#pragma unroll
                    for (int q = 0; q < 4; ++q) {
                        const float y = acc[q] + b3r[t];
                        tb[tb_off(hi * 4 + q, t2 * 16 + ln)] = bfbits(y);
                        const int row = node0 + hi * 4 + q;
                        if (row < rcnt && !iq[q])
                            OUTf[(size_t)row * H + half * 64 + t2 * 16 + ln] = y;
                    }
                }
                if (winv) {
                    us8 w0 = __builtin_bit_cast(us8, ld_tb(tb, rr, c0));
                    us8 w1 = __builtin_bit_cast(us8, ld_tb(tb, rr, c0 + 8));
                    ushort_t* op = xtra + (size_t)irk * H + half * 64 + c0;
                    *(us8*)op = w0;
                    *(us8*)(op + 8) = w1;
                }
            }
        } else {
            float* OUTf = (float*)OUT_;
            int grow[4];
#pragma unroll
            for (int q = 0; q < 4; ++q) {
                const int pos = node0 + hi * 4 + q;
                grow[q] = (pos < rcnt) ? (LIST ? rows[pos] : pos) : -1;
            }
#pragma unroll 2
            for (int t = 0; t < 8; ++t) {
                f32x4 acc = {0.f, 0.f, 0.f, 0.f};
#pragma unroll
                for (int s = 0; s < 2; ++s)
                    acc = __builtin_amdgcn_mfma_f32_16x16x32_bf16(a3[s], ld_frg(FRG, 24 + s * 8 + t, lane), acc, 0, 0, 0);
#pragma unroll
                for (int q = 0; q < 4; ++q) {
                    if (grow[q] >= 0)
                        OUTf[(size_t)grow[q] * H + t * 16 + ln] = acc[q] + b3r[t];
                }
            }
        }
    }
}

// ---------------- CSR build (two-level counting sort) + fused inv scan -------
// blocks [0,cgrid): coarse histogram of dst>>BSH. blocks [cgrid,+nchunks): iscan1.
__global__ __launch_bounds__(256) void coarse_hist_k(
    const int* __restrict__ dst, int* __restrict__ chist,
    const int* __restrict__ inv, int* __restrict__ bsumI,
    int E, int N, int cgrid)
{
    __shared__ int h[256];
    const int tid = threadIdx.x;
    if (blockIdx.x < cgrid) {
        h[tid] = 0;
        __syncthreads();
        const int base = blockIdx.x * ACH;
#pragma unroll
        for (int j = 0; j < 8; ++j) {
            const int e = base + j * 256 + tid;
            if (e < E) atomicAdd(&h[dst[e] >> BSH], 1);
        }
        __syncthreads();
        if (h[tid]) atomicAdd(&chist[tid], h[tid]);
    } else {
        const int b = blockIdx.x - cgrid;
        const int base = b * CHUNK + tid * 8;
        int sumi = 0;
#pragma unroll
        for (int j = 0; j < 8; ++j) { int i = base + j; if (i < N) sumi += inv[i]; }
        h[tid] = sumi;
        __syncthreads();
        for (int st = 128; st > 0; st >>= 1) {
            if (tid < st) h[tid] += h[tid + st];
            __syncthreads();
        }
        if (tid == 0) bsumI[b] = h[0];
    }
}

// single block: coarse-bucket scan (cbase/ccur) + inv chunk scan (bsumI, icnt)
__global__ __launch_bounds__(256) void cscan_k(
    const int* __restrict__ chist, int* __restrict__ cbase, int* __restrict__ ccur,
    int* __restrict__ bsumI, int* __restrict__ icnt,
    int nb, int E, int nchunks)
{
    __shared__ int s[256];
    const int tid = threadIdx.x;
    const int v = (tid < nb) ? chist[tid] : 0;
    s[tid] = v;
    __syncthreads();
    for (int st = 1; st < 256; st <<= 1) {
        int t = (tid >= st) ? s[tid - st] : 0;
        __syncthreads();
        s[tid] += t;
        __syncthreads();
    }
    const int excl = s[tid] - v;
    if (tid < nb) { cbase[tid] = excl; ccur[tid] = excl; }
    if (tid == 0) cbase[nb] = E;
    __syncthreads();
    const int u0 = (tid < nchunks) ? bsumI[tid] : 0;
    s[tid] = u0;
    __syncthreads();
    for (int st = 1; st < 256; st <<= 1) {
        int t = (tid >= st) ? s[tid - st] : 0;
        __syncthreads();
        s[tid] += t;
        __syncthreads();
    }
    if (tid < nchunks) bsumI[tid] = s[tid] - u0;
    if (tid == 255) icnt[0] = s[255];
}

// blocks [0,cgrid): coarse bin pass. blocks [cgrid,+nchunks): iscan3 (ilist/irank)
__global__ __launch_bounds__(256) void coarse_bin_k(
    const int* __restrict__ src, const int* __restrict__ dst,
    const int* __restrict__ r,
    int* __restrict__ ccur, unsigned* __restrict__ ebuf,
    const int* __restrict__ inv, const int* __restrict__ bsumI,
    int* __restrict__ ilist, int* __restrict__ irank,
    int E, int N, int cgrid)
{
    __shared__ int hcnt[256];
    __shared__ int gbase[256];
    __shared__ int lcur[256];
    const int tid = threadIdx.x;
    if (blockIdx.x < cgrid) {
        hcnt[tid] = 0;
        __syncthreads();
        const int base = blockIdx.x * ACH;
        unsigned v[8]; int bk[8];
#pragma unroll
        for (int j = 0; j < 8; ++j) {
            const int e = base + j * 256 + tid;
            if (e < E) {
                const int d = dst[e];
                bk[j] = d >> BSH;
                v[j] = ((unsigned)(d & (BSZ - 1)) << 18) |
                       ((unsigned)src[e] << 1) | (unsigned)r[e];
                atomicAdd(&hcnt[bk[j]], 1);
            } else bk[j] = -1;
        }
        __syncthreads();
        const int c = hcnt[tid];
        gbase[tid] = (c > 0) ? atomicAdd(&ccur[tid], c) : 0;
        lcur[tid] = 0;
        __syncthreads();
#pragma unroll
        for (int j = 0; j < 8; ++j) {
            if (bk[j] >= 0) {
                const int loc = atomicAdd(&lcur[bk[j]], 1);
                ebuf[gbase[bk[j]] + loc] = v[j];
            }
        }
    } else {
        const int b = blockIdx.x - cgrid;
        const int base = b * CHUNK + tid * 8;
        int vi[8]; int tsumi = 0;
#pragma unroll
        for (int j = 0; j < 8; ++j) {
            int t = (base + j < N) ? inv[base + j] : 0;
            vi[j] = tsumi; tsumi += t;
        }
        hcnt[tid] = tsumi;
        __syncthreads();
        for (int st = 1; st < 256; st <<= 1) {
            int val = (tid >= st) ? hcnt[tid - st] : 0;
            __syncthreads();
            hcnt[tid] += val;
            __syncthreads();
        }
        const int texclI = hcnt[tid] - tsumi + bsumI[b];
#pragma unroll
        for (int j = 0; j < 8; ++j) {
            int i = base + j;
            if (i < N && inv[i]) {
                const int rank = texclI + vi[j];
                ilist[rank] = i;
                irank[i] = rank;
            }
        }
    }
}

// fine pass: one block per 512-node bucket. LDS hist + LDS scan emit offsets;
// LDS cursors scatter packed. Output region ~16KB stays in one XCD L2.
__global__ __launch_bounds__(512) void fine_build_k(
    const unsigned* __restrict__ ebuf, const int* __restrict__ cbase,
    int* __restrict__ offsets, int* __restrict__ packed, int N, int E, int nb)
{
    __shared__ int loff[BSZ];
    __shared__ int lcur[BSZ];
    const int b = blockIdx.x, tid = threadIdx.x;
    const int lo = b << BSH;
    const int nn = min(BSZ, N - lo);
    const int rstart = cbase[b];
    const int rend   = cbase[b + 1];
    lcur[tid] = 0;
    __syncthreads();
    for (int i = rstart + tid; i < rend; i += BSZ)
        atomicAdd(&lcur[ebuf[i] >> 18], 1);
    __syncthreads();
    const int v = lcur[tid];
    loff[tid] = v;
    __syncthreads();
    for (int st = 1; st < BSZ; st <<= 1) {
        int t = (tid >= st) ? loff[tid - st] : 0;
        __syncthreads();
        loff[tid] += t;
        __syncthreads();
    }
    const int base = rstart + loff[tid] - v;     // exclusive prefix
    if (tid < nn) offsets[lo + tid] = base;
    if (b == nb - 1 && tid == 0) offsets[N] = E;
    __syncthreads();
    lcur[tid] = base;
    __syncthreads();
    for (int i = rstart + tid; i < rend; i += BSZ) {
        const unsigned w = ebuf[i];
        const int dloc = w >> 18;
        const int pos = atomicAdd(&lcur[dloc], 1);
        packed[pos] = (int)(((w & 0x3ffffu) >> 1) | ((w & 1u) << 31));
    }
}

// one wave per node: 4 rows x 16 lanes x 16B, 16 rows in flight; f32 accum;
// shfl_xor(16,32) combine; bf16 mean out. deg = offsets diff.
__global__ __launch_bounds__(256) void gather_mean_k(
    const ushort_t* __restrict__ featb, const ushort_t* __restrict__ invb,
    const int* __restrict__ offsets,
    const int* __restrict__ packed, ushort_t* __restrict__ neighb, int N)
{
    const int wv = threadIdx.x >> 6, lane = threadIdx.x & 63;
    const int n = blockIdx.x * 4 + wv;
    if (n >= N) return;
    const int start = offsets[n];
    const int d = offsets[n + 1] - start;
    const int q4 = lane >> 4;                    // row-in-group 0..3
    const size_t co = (size_t)(lane & 15) * 8;   // col base
    float a[8] = {0.f, 0.f, 0.f, 0.f, 0.f, 0.f, 0.f, 0.f};
    int k = 0;
    for (; k + 15 < d; k += 16) {
        const int p0 = packed[start + k + q4];
        const int p1 = packed[start + k + 4 + q4];
        const int p2 = packed[start + k + 8 + q4];
        const int p3 = packed[start + k + 12 + q4];
        const ushort_t* t0 = (p0 < 0) ? invb : featb;
        const ushort_t* t1 = (p1 < 0) ? invb : featb;
        const ushort_t* t2 = (p2 < 0) ? invb : featb;
        const ushort_t* t3 = (p3 < 0) ? invb : featb;
        const us8 u0 = *(const us8*)(t0 + (size_t)(p0 & 0x7fffffff) * H + co);
        const us8 u1 = *(const us8*)(t1 + (size_t)(p1 & 0x7fffffff) * H + co);
        const us8 u2 = *(const us8*)(t2 + (size_t)(p2 & 0x7fffffff) * H + co);
        const us8 u3 = *(const us8*)(t3 + (size_t)(p3 & 0x7fffffff) * H + co);
#pragma unroll
        for (int i = 0; i < 8; ++i) a[i] += (bfl(u0[i]) + bfl(u1[i])) + (bfl(u2[i]) + bfl(u3[i]));
    }
    for (; k + 7 < d; k += 8) {
        const int pA = packed[start + k + q4];
        const int pB = packed[start + k + 4 + q4];
        const ushort_t* tA = (pA < 0) ? invb : featb;
        const ushort_t* tB = (pB < 0) ? invb : featb;
        const us8 uA = *(const us8*)(tA + (size_t)(pA & 0x7fffffff) * H + co);
        const us8 uB = *(const us8*)(tB + (size_t)(pB & 0x7fffffff) * H + co);
#pragma unroll
        for (int i = 0; i < 8; ++i) a[i] += bfl(uA[i]) + bfl(uB[i]);
    }
    if (k + 3 < d) {
        const int p = packed[start + k + q4];
        const ushort_t* t = (p < 0) ? invb : featb;
        const us8 u = *(const us8*)(t + (size_t)(p & 0x7fffffff) * H + co);
#pragma unroll
        for (int i = 0; i < 8; ++i) a[i] += bfl(u[i]);
        k += 4;
    }
    const int rem = d - k;
    if (q4 < rem) {
        const int p = packed[start + k + q4];
        const ushort_t* t = (p < 0) ? invb : featb;
        const us8 u = *(const us8*)(t + (size_t)(p & 0x7fffffff) * H + co);
#pragma unroll
        for (int i = 0; i < 8; ++i) a[i] += bfl(u[i]);
    }
#pragma unroll
    for (int i = 0; i < 8; ++i) {
        a[i] += __shfl_xor(a[i], 16);
        a[i] += __shfl_xor(a[i], 32);
    }
    if (q4 == 0) {
        const float scl = 1.0f / (float)max(d, 1);
        us8 o;
#pragma unroll
        for (int i = 0; i < 8; ++i) o[i] = bfbits(a[i] * scl);
        *(us8*)(neighb + (size_t)n * H + co) = o;
    }
}

extern "C" void kernel_launch(void* const* d_in, const int* in_sizes, int n_in,
                              void* d_out, int out_size, void* d_ws, size_t ws_size,
                              hipStream_t stream) {
    const float* feat = (const float*)d_in[0];
    const int*   src  = (const int*)d_in[1];
    const int*   dst  = (const int*)d_in[2];
    const int*   r    = (const int*)d_in[3];
    const int*   inv  = (const int*)d_in[4];
    const float* iw1 = (const float*)d_in[5],  *ib1 = (const float*)d_in[6];
    const float* iw2 = (const float*)d_in[7],  *ib2 = (const float*)d_in[8];
    const float* iw3 = (const float*)d_in[9],  *ib3 = (const float*)d_in[10];
    const float* aw1 = (const float*)d_in[11], *ab1 = (const float*)d_in[12];
    const float* aw2 = (const float*)d_in[13], *ab2 = (const float*)d_in[14];
    const float* aw3 = (const float*)d_in[15], *ab3 = (const float*)d_in[16];

    const int N = in_sizes[4];   // inv is [N]
    const int E = in_sizes[1];   // src is [E]

    ushort_t* featb  = (ushort_t*)d_ws;             // N*H bf16; dead after gather
    ushort_t* resb   = featb;                       //   ...aliased by resb (pass4/5)
    ushort_t* invb   = featb + (size_t)N * H;       // N*H bf16
    ushort_t* neighb = invb + (size_t)N * H;        // N*H bf16
    int* offsets = (int*)(neighb + (size_t)N * H);  // N+1
    int* ilist   = offsets + (N + 1);
    int* irank   = ilist + N;
    unsigned* ebuf = (unsigned*)(irank + N);
    int* packed  = (int*)(ebuf + E);
    ushort_t* frg = (ushort_t*)(packed + E);        // 80 frags x 512 us = 80 KB
    int* chist   = (int*)(frg + 80 * 512);
    int* cbase   = chist + 256;                     // 257
    int* ccur    = cbase + 257;
    int* bsumI   = ccur + 256;
    int* icnt    = bsumI + 256;

    ushort_t* frg_inv = frg;
    ushort_t* frg_and = frg + 40 * 512;

    const int nchunks = (N + CHUNK - 1) / CHUNK;
    const int ntiles  = (N + 15) / 16;
    const int NB      = (N + BSZ - 1) / BSZ;        // coarse buckets (<=256)
    const int cgrid   = (E + ACH - 1) / ACH;
    const int g1      = (ntiles + NW - 1) / NW;     // one tile per wave

    hipMemsetAsync(chist, 0, 256 * sizeof(int), stream);

    // 0) pre-pack weight B-fragments (both sets) into global frag table
    prep_frags_k<<<20, 256, 0, stream>>>(iw1, iw2, iw3, aw1, aw2, aw3, frg);
    // 1) invb = bf16(mlp_inv(feat)); featb = bf16(feat)
    mlp3_t<false, true, true, false, false><<<g1, 512, 0, stream>>>(
        feat, frg_inv, ib1, ib2, ib3, invb, featb,
        nullptr, nullptr, nullptr, nullptr, N, ntiles);
    // 2) CSR build: coarse hist (+iscan1) -> scan (+iscan2) -> bin (+iscan3) -> fine
    coarse_hist_k<<<cgrid + nchunks, 256, 0, stream>>>(dst, chist, inv, bsumI, E, N, cgrid);
    cscan_k<<<1, 256, 0, stream>>>(chist, cbase, ccur, bsumI, icnt, NB, E, nchunks);
    coarse_bin_k<<<cgrid + nchunks, 256, 0, stream>>>(src, dst, r, ccur, ebuf,
                                                      inv, bsumI, ilist, irank, E, N, cgrid);
    fine_build_k<<<NB, BSZ, 0, stream>>>(ebuf, cbase, offsets, packed, N, E, NB);
    // 3) neighb = bf16(mean of messages)
    gather_mean_k<<<(N + 3) / 4, 256, 0, stream>>>(featb, invb, offsets,
                                                   packed, neighb, N);
    // 4) res = mlp_and(neighb): non-inv rows f32 -> d_out, inv rows bf16 -> resb
    mlp3_t<true, false, false, false, true><<<g1, 512, 0, stream>>>(
        neighb, frg_and, ab1, ab2, ab3, d_out, resb,
        nullptr, nullptr, inv, irank, N, ntiles);
    // 5) d_out[ilist] = mlp_inv(resb)  (compact bf16 in, scattered f32 out)
    mlp3_t<true, false, false, true, false><<<g1, 512, 0, stream>>>(
        resb, frg_inv, ib1, ib2, ib3, d_out, nullptr,
        ilist, icnt, nullptr, nullptr, N, ntiles);
}

// Round 9
// 154.978 us; speedup vs baseline: 2.8701x; 1.0540x over previous
//
#include <hip/hip_runtime.h>

// FuncConv: out = select(inv, mlp_inv(res), res); res = mlp_and(mean_dst(msg));
// msg = select(r, mlp_inv(feat[src]), feat[src]).
// R8: (a) fuse pass4+pass5 -> mlp45_k: res kept in regs/LDS, non-inv rows f32
//     out + bf16 res -> per-wave 16x128 LDS buffer -> mlp_inv -> inv rows f32.
//     Kills resb round-trip (25.6MB), ilist/irank/iscan, one launch.
// (b) heterogeneous fused launches: {prep || coarse_hist}, {fine_build||pass1}.
//     10 -> 7 dispatches.
//
// ws: featb[N*H bf16] invb[N*H bf16] neighb[N*H bf16]
//     offsets[N+1] ebuf[E] packed[E] frg[80*512 us] chist[256] cbase[257] ccur[256]

#define H 128
#define HH 64
#define NW 8      // waves per MLP block
#define BSH 9     // log2 nodes per coarse bucket
#define BSZ 512   // nodes per coarse bucket
#define ACH 2048  // edges per coarse block

typedef float f32x4 __attribute__((ext_vector_type(4)));
typedef __bf16 bf16x8 __attribute__((ext_vector_type(8)));
typedef unsigned short us8 __attribute__((ext_vector_type(8)));
typedef unsigned short ushort_t;

__device__ __forceinline__ unsigned short bfbits(float f) {
    __bf16 h = (__bf16)f;                       // RNE convert
    return __builtin_bit_cast(unsigned short, h);
}
__device__ __forceinline__ bf16x8 as_bf16x8(us8 v) {
    return __builtin_bit_cast(bf16x8, v);
}
__device__ __forceinline__ float bfl(unsigned short u) {
    return __builtin_bit_cast(float, ((unsigned)u) << 16);
}

// per-wave transpose buffers, XOR-swizzled (byte ^= (row&7)<<4; 16B groups)
__device__ __forceinline__ int tb_off(int m, int j) {      // 16 x 64 bf16
    return m * 64 + ((((j * 2) ^ ((m & 7) << 4))) >> 1);
}
__device__ __forceinline__ int tb2_off(int m, int j) {     // 16 x 128 bf16
    return m * 128 + ((((j * 2) ^ ((m & 7) << 4))) >> 1);
}
__device__ __forceinline__ bf16x8 ld_tb(const unsigned short* tb, int m, int j0) {
    return as_bf16x8(*(const us8*)&tb[tb_off(m, j0)]);
}
__device__ __forceinline__ bf16x8 ld_tb2(const unsigned short* tb, int m, int j0) {
    return as_bf16x8(*(const us8*)&tb[tb2_off(m, j0)]);
}
// weight B-fragment from global (L1/L2-hot, 40KB working set per MLP)
__device__ __forceinline__ bf16x8 ld_frg(const ushort_t* __restrict__ FRG, int fid, int lane) {
    return as_bf16x8(*(const us8*)&FRG[(fid * 64 + lane) * 8]);
}

// ---------------- fused: coarse dst-histogram || weight frag pre-pack --------
// blocks [0,cgrid): LDS-aggregated histogram of dst>>BSH into chist.
// blocks [cgrid,cgrid+20): pack 80 MFMA B-frags (inv set then and set).
__global__ __launch_bounds__(256) void prep_hist_k(
    const int* __restrict__ dst, int* __restrict__ chist,
    const float* __restrict__ iw1, const float* __restrict__ iw2,
    const float* __restrict__ iw3,
    const float* __restrict__ aw1, const float* __restrict__ aw2,
    const float* __restrict__ aw3,
    ushort_t* __restrict__ frg, int E, int cgrid)
{
    __shared__ int h[256];
    const int tid = threadIdx.x;
    if (blockIdx.x < cgrid) {
        h[tid] = 0;
        __syncthreads();
        const int base = blockIdx.x * ACH;
#pragma unroll
        for (int j = 0; j < 8; ++j) {
            const int e = base + j * 256 + tid;
            if (e < E) atomicAdd(&h[dst[e] >> BSH], 1);
        }
        __syncthreads();
        if (h[tid]) atomicAdd(&chist[tid], h[tid]);
    } else {
        const int g = (blockIdx.x - cgrid) * 256 + tid;     // 80*64 = 5120
        const int fid2 = g >> 6;
        if (fid2 >= 80) return;
        const int lane = g & 63;
        const int ln = lane & 15, hi = lane >> 4;
        const int set = fid2 / 40;
        const int fid = fid2 - set * 40;
        const float* w; int inF, s, t;
        if (fid < 16)      { w = set ? aw1 : iw1; inF = H;  s = fid >> 2;        t = fid & 3; }
        else if (fid < 24) { w = set ? aw2 : iw2; inF = HH; s = (fid - 16) >> 2; t = (fid - 16) & 3; }
        else               { w = set ? aw3 : iw3; inF = HH; s = (fid - 24) >> 3; t = (fid - 24) & 7; }
        const float* p = w + (size_t)(t * 16 + ln) * inF + (s * 32 + hi * 8);
        f32x4 a = *(const f32x4*)p;
        f32x4 b = *(const f32x4*)(p + 4);
        ushort_t* d = &frg[(size_t)(fid2 * 64 + lane) * 8];
        d[0] = bfbits(a[0]); d[1] = bfbits(a[1]); d[2] = bfbits(a[2]); d[3] = bfbits(a[3]);
        d[4] = bfbits(b[0]); d[5] = bfbits(b[1]); d[6] = bfbits(b[2]); d[7] = bfbits(b[3]);
    }
}

// single block: coarse-bucket exclusive scan -> cbase/ccur
__global__ __launch_bounds__(256) void cscan_k(
    const int* __restrict__ chist, int* __restrict__ cbase, int* __restrict__ ccur,
    int nb, int E)
{
    __shared__ int s[256];
    const int tid = threadIdx.x;
    const int v = (tid < nb) ? chist[tid] : 0;
    s[tid] = v;
    __syncthreads();
    for (int st = 1; st < 256; st <<= 1) {
        int t = (tid >= st) ? s[tid - st] : 0;
        __syncthreads();
        s[tid] += t;
        __syncthreads();
    }
    const int excl = s[tid] - v;
    if (tid < nb) { cbase[tid] = excl; ccur[tid] = excl; }
    if (tid == 0) cbase[nb] = E;
}

// coarse pass: bin edges by dst>>BSH; block-local LDS hist + one reservation
// atomic per (block,bucket); entry = (dloc<<18)|(src<<1)|r  (src < 2^17)
__global__ __launch_bounds__(256) void coarse_bin_k(
    const int* __restrict__ src, const int* __restrict__ dst,
    const int* __restrict__ r,
    int* __restrict__ ccur, unsigned* __restrict__ ebuf, int E)
{
    __shared__ int hcnt[256];
    __shared__ int gbase[256];
    __shared__ int lcur[256];
    const int tid = threadIdx.x;
    hcnt[tid] = 0;
    __syncthreads();
    const int base = blockIdx.x * ACH;
    unsigned v[8]; int bk[8];
#pragma unroll
    for (int j = 0; j < 8; ++j) {
        const int e = base + j * 256 + tid;
        if (e < E) {
            const int d = dst[e];
            bk[j] = d >> BSH;
            v[j] = ((unsigned)(d & (BSZ - 1)) << 18) |
                   ((unsigned)src[e] << 1) | (unsigned)r[e];
            atomicAdd(&hcnt[bk[j]], 1);
        } else bk[j] = -1;
    }
    __syncthreads();
    const int c = hcnt[tid];
    gbase[tid] = (c > 0) ? atomicAdd(&ccur[tid], c) : 0;
    lcur[tid] = 0;
    __syncthreads();
#pragma unroll
    for (int j = 0; j < 8; ++j) {
        if (bk[j] >= 0) {
            const int loc = atomicAdd(&lcur[bk[j]], 1);
            ebuf[gbase[bk[j]] + loc] = v[j];
        }
    }
}

// ---------------- fused: fine_build || MLP pass 1 -----------------------------
// blocks [0,NB): per 512-node bucket LDS hist/scan -> offsets, packed.
// blocks [NB,NB+g1): pass1: invb = bf16(mlp_inv(feat)); featb = bf16(feat).
__global__ __launch_bounds__(512) void pass1_fine_k(
    const float* __restrict__ X,
    const ushort_t* __restrict__ FRG,
    const float* __restrict__ B1, const float* __restrict__ B2,
    const float* __restrict__ B3,
    ushort_t* __restrict__ invb, ushort_t* __restrict__ featb,
    const unsigned* __restrict__ ebuf, const int* __restrict__ cbase,
    int* __restrict__ offsets, int* __restrict__ packed,
    int N, int E, int NB, int ntiles)
{
    __shared__ __align__(16) unsigned short TBs[NW * 16 * 64];  // 16 KB
    const int tid = threadIdx.x;

    if (blockIdx.x < NB) {
        // ------- fine_build body (uses TBs as two int[512] arrays) ----------
        int* loff = (int*)TBs;
        int* lcur = loff + BSZ;
        const int b = blockIdx.x;
        const int lo = b << BSH;
        const int nn = min(BSZ, N - lo);
        const int rstart = cbase[b];
        const int rend   = cbase[b + 1];
        lcur[tid] = 0;
        __syncthreads();
        for (int i = rstart + tid; i < rend; i += BSZ)
            atomicAdd(&lcur[ebuf[i] >> 18], 1);
        __syncthreads();
        const int v = lcur[tid];
        loff[tid] = v;
        __syncthreads();
        for (int st = 1; st < BSZ; st <<= 1) {
            int t = (tid >= st) ? loff[tid - st] : 0;
            __syncthreads();
            loff[tid] += t;
            __syncthreads();
        }
        const int base = rstart + loff[tid] - v;     // exclusive prefix
        if (tid < nn) offsets[lo + tid] = base;
        if (b == NB - 1 && tid == 0) offsets[N] = E;
        __syncthreads();
        lcur[tid] = base;
        __syncthreads();
        for (int i = rstart + tid; i < rend; i += BSZ) {
            const unsigned w = ebuf[i];
            const int dloc = w >> 18;
            const int pos = atomicAdd(&lcur[dloc], 1);
            packed[pos] = (int)(((w & 0x3ffffu) >> 1) | ((w & 1u) << 31));
        }
        return;
    }

    // ------- MLP pass-1 body (barrier-free, one tile per wave) --------------
    const int wv   = tid >> 6;
    const int lane = tid & 63;
    const int ln   = lane & 15;
    const int hi   = lane >> 4;

    const int tile = (blockIdx.x - NB) * NW + wv;
    if (tile >= ntiles) return;

    float b1r[4], b2r[4], b3r[8];
#pragma unroll
    for (int t = 0; t < 4; ++t) b1r[t] = B1[t * 16 + ln];
#pragma unroll
    for (int t = 0; t < 4; ++t) b2r[t] = B2[t * 16 + ln];
#pragma unroll
    for (int t = 0; t < 8; ++t) b3r[t] = B3[t * 16 + ln];

    unsigned short* tb = &TBs[wv * 16 * 64];
    const int node0 = tile * 16;
    const int lpos  = min(node0 + ln, N - 1);
    const size_t ro = (size_t)lpos * H;

    bf16x8 a1[4];
#pragma unroll
    for (int s = 0; s < 4; ++s) {
        f32x4 u = *(const f32x4*)(X + ro + s * 32 + hi * 8);
        f32x4 v = *(const f32x4*)(X + ro + s * 32 + hi * 8 + 4);
        bf16x8 f;
        f[0] = (__bf16)u[0]; f[1] = (__bf16)u[1]; f[2] = (__bf16)u[2]; f[3] = (__bf16)u[3];
        f[4] = (__bf16)v[0]; f[5] = (__bf16)v[1]; f[6] = (__bf16)v[2]; f[7] = (__bf16)v[3];
        a1[s] = f;
        *(us8*)(featb + ro + s * 32 + hi * 8) = __builtin_bit_cast(us8, f);
    }

    // layer 1
#pragma unroll 2
    for (int t = 0; t < 4; ++t) {
        f32x4 acc = {0.f, 0.f, 0.f, 0.f};
#pragma unroll
        for (int s = 0; s < 4; ++s)
            acc = __builtin_amdgcn_mfma_f32_16x16x32_bf16(a1[s], ld_frg(FRG, s * 4 + t, lane), acc, 0, 0, 0);
#pragma unroll
        for (int q = 0; q < 4; ++q) {
            float y = acc[q] + b1r[t];
            y = (y >= 0.f) ? y : 0.01f * y;
            tb[tb_off(hi * 4 + q, t * 16 + ln)] = bfbits(y);
        }
    }

    // layer 2
    bf16x8 a2[2];
#pragma unroll
    for (int s = 0; s < 2; ++s) a2[s] = ld_tb(tb, ln, s * 32 + hi * 8);
#pragma unroll 2
    for (int t = 0; t < 4; ++t) {
        f32x4 acc = {0.f, 0.f, 0.f, 0.f};
#pragma unroll
        for (int s = 0; s < 2; ++s)
            acc = __builtin_amdgcn_mfma_f32_16x16x32_bf16(a2[s], ld_frg(FRG, 16 + s * 4 + t, lane), acc, 0, 0, 0);
#pragma unroll
        for (int q = 0; q < 4; ++q) {
            float y = acc[q] + b2r[t];
            y = (y >= 0.f) ? y : 0.01f * y;
            tb[tb_off(hi * 4 + q, t * 16 + ln)] = bfbits(y);
        }
    }

    // layer 3 -> bf16 invb, staged through LDS for coalesced 16B stores
    bf16x8 a3[2];
#pragma unroll
    for (int s = 0; s < 2; ++s) a3[s] = ld_tb(tb, ln, s * 32 + hi * 8);
#pragma unroll
    for (int half = 0; half < 2; ++half) {
#pragma unroll 2
        for (int t2 = 0; t2 < 4; ++t2) {
            const int t = half * 4 + t2;
            f32x4 acc = {0.f, 0.f, 0.f, 0.f};
#pragma unroll
            for (int s = 0; s < 2; ++s)
                acc = __builtin_amdgcn_mfma_f32_16x16x32_bf16(a3[s], ld_frg(FRG, 24 + s * 8 + t, lane), acc, 0, 0, 0);
#pragma unroll
            for (int q = 0; q < 4; ++q)
                tb[tb_off(hi * 4 + q, t2 * 16 + ln)] = bfbits(acc[q] + b3r[t]);
        }
        const int rr = lane >> 2, c0 = (lane & 3) * 16;
        if (node0 + rr < N) {
            us8 w0 = __builtin_bit_cast(us8, ld_tb(tb, rr, c0));
            us8 w1 = __builtin_bit_cast(us8, ld_tb(tb, rr, c0 + 8));
            ushort_t* op = invb + (size_t)(node0 + rr) * H + half * 64 + c0;
            *(us8*)op = w0;
            *(us8*)(op + 8) = w1;
        }
    }
}

// ---------------- fused pass 4+5: res = mlp_and(neigh); out = inv?mlp_inv(res):res
// per wave: 16x128 LDS buffer holds bf16(res); non-inv rows written f32 from
// phase-A acc; phase B reruns mlp_inv from the LDS copy; inv rows written f32.
__global__ __launch_bounds__(512) void mlp45_k(
    const ushort_t* __restrict__ Xb,          // neighb, bf16
    const ushort_t* __restrict__ FRGa,        // and frags
    const ushort_t* __restrict__ FRGi,        // inv frags
    const float* __restrict__ A1, const float* __restrict__ A2,
    const float* __restrict__ A3,
    const float* __restrict__ I1, const float* __restrict__ I2,
    const float* __restrict__ I3,
    float* __restrict__ OUT,
    const int* __restrict__ invp,
    int nrows, int ntiles)
{
    __shared__ __align__(16) unsigned short TB2[NW * 16 * 128];  // 32 KB
    const int tid  = threadIdx.x;
    const int wv   = tid >> 6;
    const int lane = tid & 63;
    const int ln   = lane & 15;
    const int hi   = lane >> 4;

    const int tile = blockIdx.x * NW + wv;
    if (tile >= ntiles) return;
    const int node0 = tile * 16;
    unsigned short* tb = &TB2[wv * 16 * 128];

    int iq[4];
#pragma unroll
    for (int q = 0; q < 4; ++q) {
        const int row = node0 + hi * 4 + q;
        iq[q] = (row < nrows) ? invp[row] : 1;
    }

    // ---- phase A: mlp_and ----
    {
        float b1r[4], b2r[4], b3r[8];
#pragma unroll
        for (int t = 0; t < 4; ++t) b1r[t] = A1[t * 16 + ln];
#pragma unroll
        for (int t = 0; t < 4; ++t) b2r[t] = A2[t * 16 + ln];
#pragma unroll
        for (int t = 0; t < 8; ++t) b3r[t] = A3[t * 16 + ln];

        const int lpos  = min(node0 + ln, nrows - 1);
        const size_t ro = (size_t)lpos * H;
        bf16x8 a1[4];
#pragma unroll
        for (int s = 0; s < 4; ++s)
            a1[s] = as_bf16x8(*(const us8*)(Xb + ro + s * 32 + hi * 8));

#pragma unroll 2
        for (int t = 0; t < 4; ++t) {
            f32x4 acc = {0.f, 0.f, 0.f, 0.f};
#pragma unroll
            for (int s = 0; s < 4; ++s)
                acc = __builtin_amdgcn_mfma_f32_16x16x32_bf16(a1[s], ld_frg(FRGa, s * 4 + t, lane), acc, 0, 0, 0);
#pragma unroll
            for (int q = 0; q < 4; ++q) {
                float y = acc[q] + b1r[t];
                y = (y >= 0.f) ? y : 0.01f * y;
                tb[tb2_off(hi * 4 + q, t * 16 + ln)] = bfbits(y);
            }
        }

        bf16x8 a2[2];
#pragma unroll
        for (int s = 0; s < 2; ++s) a2[s] = ld_tb2(tb, ln, s * 32 + hi * 8);
#pragma unroll 2
        for (int t = 0; t < 4; ++t) {
            f32x4 acc = {0.f, 0.f, 0.f, 0.f};
#pragma unroll
            for (int s = 0; s < 2; ++s)
                acc = __builtin_amdgcn_mfma_f32_16x16x32_bf16(a2[s], ld_frg(FRGa, 16 + s * 4 + t, lane), acc, 0, 0, 0);
#pragma unroll
            for (int q = 0; q < 4; ++q) {
                float y = acc[q] + b2r[t];
                y = (y >= 0.f) ? y : 0.01f * y;
                tb[tb2_off(hi * 4 + q, t * 16 + ln)] = bfbits(y);
            }
        }

        bf16x8 a3[2];
#pragma unroll
        for (int s = 0; s < 2; ++s) a3[s] = ld_tb2(tb, ln, s * 32 + hi * 8);
#pragma unroll 2
        for (int t = 0; t < 8; ++t) {
            f32x4 acc = {0.f, 0.f, 0.f, 0.f};
#pragma unroll
            for (int s = 0; s < 2; ++s)
                acc = __builtin_amdgcn_mfma_f32_16x16x32_bf16(a3[s], ld_frg(FRGa, 24 + s * 8 + t, lane), acc, 0, 0, 0);
#pragma unroll
            for (int q = 0; q < 4; ++q) {
                const float y = acc[q] + b3r[t];
                tb[tb2_off(hi * 4 + q, t * 16 + ln)] = bfbits(y);   // res, bf16
                const int row = node0 + hi * 4 + q;
                if (row < nrows && !iq[q])
                    OUT[(size_t)row * H + t * 16 + ln] = y;          // exact f32
            }
        }
    }

    // ---- phase B: mlp_inv(res) for inv rows ----
    {
        float b1r[4], b2r[4], b3r[8];
#pragma unroll
        for (int t = 0; t < 4; ++t) b1r[t] = I1[t * 16 + ln];
#pragma unroll
        for (int t = 0; t < 4; ++t) b2r[t] = I2[t * 16 + ln];
#pragma unroll
        for (int t = 0; t < 8; ++t) b3r[t] = I3[t * 16 + ln];

        bf16x8 a1[4];
#pragma unroll
        for (int s = 0; s < 4; ++s)
            a1[s] = ld_tb2(tb, ln, s * 32 + hi * 8);   // loads complete before writes below

#pragma unroll 2
        for (int t = 0; t < 4; ++t) {
            f32x4 acc = {0.f, 0.f, 0.f, 0.f};
#pragma unroll
            for (int s = 0; s < 4; ++s)
                acc = __builtin_amdgcn_mfma_f32_16x16x32_bf16(a1[s], ld_frg(FRGi, s * 4 + t, lane), acc, 0, 0, 0);
#pragma unroll
            for (int q = 0; q < 4; ++q) {
                float y = acc[q] + b1r[t];
                y = (y >= 0.f) ? y : 0.01f * y;
                tb[tb2_off(hi * 4 + q, t * 16 + ln)] = bfbits(y);
            }
        }

        bf16x8 a2[2];
#pragma unroll
        for (int s = 0; s < 2; ++s) a2[s] = ld_tb2(tb, ln, s * 32 + hi * 8);
#pragma unroll 2
        for (int t = 0; t < 4; ++t) {
            f32x4 acc = {0.f, 0.f, 0.f, 0.f};
#pragma unroll
            for (int s = 0; s < 2; ++s)
                acc = __builtin_amdgcn_mfma_f32_16x16x32_bf16(a2[s], ld_frg(FRGi, 16 + s * 4 + t, lane), acc, 0, 0, 0);
#pragma unroll
            for (int q = 0; q < 4; ++q) {
                float y = acc[q] + b2r[t];
                y = (y >= 0.f) ? y : 0.01f * y;
                tb[tb2_off(hi * 4 + q, t * 16 + ln)] = bfbits(y);
            }
        }

        bf16x8 a3[2];
#pragma unroll
        for (int s = 0; s < 2; ++s) a3[s] = ld_tb2(tb, ln, s * 32 + hi * 8);
#pragma unroll 2
        for (int t = 0; t < 8; ++t) {
            f32x4 acc = {0.f, 0.f, 0.f, 0.f};
#pragma unroll
            for (int s = 0; s < 2; ++s)
                acc = __builtin_amdgcn_mfma_f32_16x16x32_bf16(a3[s], ld_frg(FRGi, 24 + s * 8 + t, lane), acc, 0, 0, 0);
#pragma unroll
            for (int q = 0; q < 4; ++q) {
                const int row = node0 + hi * 4 + q;
                if (row < nrows && iq[q])
                    OUT[(size_t)row * H + t * 16 + ln] = acc[q] + b3r[t];
            }
        }
    }
}

// one wave per node: 4 rows x 16 lanes x 16B, 16 rows in flight; f32 accum;
// shfl_xor(16,32) combine; bf16 mean out. deg = offsets diff.
__global__ __launch_bounds__(256) void gather_mean_k(
    const ushort_t* __restrict__ featb, const ushort_t* __restrict__ invb,
    const int* __restrict__ offsets,
    const int* __restrict__ packed, ushort_t* __restrict__ neighb, int N)
{
    const int wv = threadIdx.x >> 6, lane = threadIdx.x & 63;
    const int n = blockIdx.x * 4 + wv;
    if (n >= N) return;
    const int start = offsets[n];
    const int d = offsets[n + 1] - start;
    const int q4 = lane >> 4;                    // row-in-group 0..3
    const size_t co = (size_t)(lane & 15) * 8;   // col base
    float a[8] = {0.f, 0.f, 0.f, 0.f, 0.f, 0.f, 0.f, 0.f};
    int k = 0;
    for (; k + 15 < d; k += 16) {
        const int p0 = packed[start + k + q4];
        const int p1 = packed[start + k + 4 + q4];
        const int p2 = packed[start + k + 8 + q4];
        const int p3 = packed[start + k + 12 + q4];
        const ushort_t* t0 = (p0 < 0) ? invb : featb;
        const ushort_t* t1 = (p1 < 0) ? invb : featb;
        const ushort_t* t2 = (p2 < 0) ? invb : featb;
        const ushort_t* t3 = (p3 < 0) ? invb : featb;
        const us8 u0 = *(const us8*)(t0 + (size_t)(p0 & 0x7fffffff) * H + co);
        const us8 u1 = *(const us8*)(t1 + (size_t)(p1 & 0x7fffffff) * H + co);
        const us8 u2 = *(const us8*)(t2 + (size_t)(p2 & 0x7fffffff) * H + co);
        const us8 u3 = *(const us8*)(t3 + (size_t)(p3 & 0x7fffffff) * H + co);
#pragma unroll
        for (int i = 0; i < 8; ++i) a[i] += (bfl(u0[i]) + bfl(u1[i])) + (bfl(u2[i]) + bfl(u3[i]));
    }
    for (; k + 7 < d; k += 8) {
        const int pA = packed[start + k + q4];
        const int pB = packed[start + k + 4 + q4];
        const ushort_t* tA = (pA < 0) ? invb : featb;
        const ushort_t* tB = (pB < 0) ? invb : featb;
        const us8 uA = *(const us8*)(tA + (size_t)(pA & 0x7fffffff) * H + co);
        const us8 uB = *(const us8*)(tB + (size_t)(pB & 0x7fffffff) * H + co);
#pragma unroll
        for (int i = 0; i < 8; ++i) a[i] += bfl(uA[i]) + bfl(uB[i]);
    }
    if (k + 3 < d) {
        const int p = packed[start + k + q4];
        const ushort_t* t = (p < 0) ? invb : featb;
        const us8 u = *(const us8*)(t + (size_t)(p & 0x7fffffff) * H + co);
#pragma unroll
        for (int i = 0; i < 8; ++i) a[i] += bfl(u[i]);
        k += 4;
    }
    const int rem = d - k;
    if (q4 < rem) {
        const int p = packed[start + k + q4];
        const ushort_t* t = (p < 0) ? invb : featb;
        const us8 u = *(const us8*)(t + (size_t)(p & 0x7fffffff) * H + co);
#pragma unroll
        for (int i = 0; i < 8; ++i) a[i] += bfl(u[i]);
    }
#pragma unroll
    for (int i = 0; i < 8; ++i) {
        a[i] += __shfl_xor(a[i], 16);
        a[i] += __shfl_xor(a[i], 32);
    }
    if (q4 == 0) {
        const float scl = 1.0f / (float)max(d, 1);
        us8 o;
#pragma unroll
        for (int i = 0; i < 8; ++i) o[i] = bfbits(a[i] * scl);
        *(us8*)(neighb + (size_t)n * H + co) = o;
    }
}

extern "C" void kernel_launch(void* const* d_in, const int* in_sizes, int n_in,
                              void* d_out, int out_size, void* d_ws, size_t ws_size,
                              hipStream_t stream) {
    const float* feat = (const float*)d_in[0];
    const int*   src  = (const int*)d_in[1];
    const int*   dst  = (const int*)d_in[2];
    const int*   r    = (const int*)d_in[3];
    const int*   inv  = (const int*)d_in[4];
    const float* iw1 = (const float*)d_in[5],  *ib1 = (const float*)d_in[6];
    const float* iw2 = (const float*)d_in[7],  *ib2 = (const float*)d_in[8];
    const float* iw3 = (const float*)d_in[9],  *ib3 = (const float*)d_in[10];
    const float* aw1 = (const float*)d_in[11], *ab1 = (const float*)d_in[12];
    const float* aw2 = (const float*)d_in[13], *ab2 = (const float*)d_in[14];
    const float* aw3 = (const float*)d_in[15], *ab3 = (const float*)d_in[16];

    const int N = in_sizes[4];   // inv is [N]
    const int E = in_sizes[1];   // src is [E]

    ushort_t* featb  = (ushort_t*)d_ws;             // N*H bf16
    ushort_t* invb   = featb + (size_t)N * H;       // N*H bf16
    ushort_t* neighb = invb + (size_t)N * H;        // N*H bf16
    int* offsets = (int*)(neighb + (size_t)N * H);  // N+1
    unsigned* ebuf = (unsigned*)(offsets + (N + 1));
    int* packed  = (int*)(ebuf + E);
    ushort_t* frg = (ushort_t*)(packed + E);        // 80 frags x 512 us = 80 KB
    int* chist   = (int*)(frg + 80 * 512);
    int* cbase   = chist + 256;                     // 257
    int* ccur    = cbase + 257;

    ushort_t* frg_inv = frg;
    ushort_t* frg_and = frg + 40 * 512;

    const int ntiles = (N + 15) / 16;
    const int NB     = (N + BSZ - 1) / BSZ;         // coarse buckets (<=256)
    const int cgrid  = (E + ACH - 1) / ACH;
    const int g1     = (ntiles + NW - 1) / NW;      // one tile per wave

    hipMemsetAsync(chist, 0, 256 * sizeof(int), stream);

    // 1) coarse histogram || weight frag pre-pack
    prep_hist_k<<<cgrid + 20, 256, 0, stream>>>(dst, chist, iw1, iw2, iw3,
                                                aw1, aw2, aw3, frg, E, cgrid);
    // 2) coarse-bucket scan
    cscan_k<<<1, 256, 0, stream>>>(chist, cbase, ccur, NB, E);
    // 3) coarse bin pass
    coarse_bin_k<<<cgrid, 256, 0, stream>>>(src, dst, r, ccur, ebuf, E);
    // 4) fine CSR build || pass1 (invb = bf16(mlp_inv(feat)), featb = bf16(feat))
    pass1_fine_k<<<NB + g1, 512, 0, stream>>>(feat, frg_inv, ib1, ib2, ib3,
                                              invb, featb, ebuf, cbase,
                                              offsets, packed, N, E, NB, ntiles);
    // 5) neighb = bf16(mean of messages by dst)
    gather_mean_k<<<(N + 3) / 4, 256, 0, stream>>>(featb, invb, offsets,
                                                   packed, neighb, N);
    // 6) fused: res = mlp_and(neighb); out = inv ? mlp_inv(res) : res
    mlp45_k<<<g1, 512, 0, stream>>>(neighb, frg_and, frg_inv,
                                    ab1, ab2, ab3, ib1, ib2, ib3,
                                    (float*)d_out, inv, N, ntiles);
}

// Round 10
// 145.571 us; speedup vs baseline: 3.0556x; 1.0646x over previous
//
#include <hip/hip_runtime.h>

// FuncConv: out = select(inv, mlp_inv(res), res); res = mlp_and(mean_dst(msg));
// msg = select(r, mlp_inv(feat[src]), feat[src]).
// R9: M-blocking in the MLPs — each wave computes TWO 16-row tiles sharing
// every weight-frag load (frag L2 traffic halved, 2 indep acc chains for
// latency hiding). mlp45_k: 256-thr/4-wave blocks, 32KB LDS. pass1 MLP:
// 512-thr/8-wave, 32KB LDS. R8 counters showed mlp45 at 44us vs 11us traffic
// floor with ~500MB of L2 frag re-reads (1 MFMA per 1KB frag load).
//
// ws: featb[N*H bf16] invb[N*H bf16] neighb[N*H bf16]
//     offsets[N+1] ebuf[E] packed[E] frg[80*512 us] chist[256] cbase[257] ccur[256]

#define H 128
#define HH 64
#define BSH 9     // log2 nodes per coarse bucket
#define BSZ 512   // nodes per coarse bucket
#define ACH 2048  // edges per coarse block

typedef float f32x4 __attribute__((ext_vector_type(4)));
typedef __bf16 bf16x8 __attribute__((ext_vector_type(8)));
typedef unsigned short us8 __attribute__((ext_vector_type(8)));
typedef unsigned short ushort_t;

__device__ __forceinline__ unsigned short bfbits(float f) {
    __bf16 h = (__bf16)f;                       // RNE convert
    return __builtin_bit_cast(unsigned short, h);
}
__device__ __forceinline__ bf16x8 as_bf16x8(us8 v) {
    return __builtin_bit_cast(bf16x8, v);
}
__device__ __forceinline__ float bfl(unsigned short u) {
    return __builtin_bit_cast(float, ((unsigned)u) << 16);
}

// per-wave transpose buffers, XOR-swizzled (byte ^= (row&7)<<4; 16B groups)
__device__ __forceinline__ int tb_off(int m, int j) {      // 16 x 64 bf16
    return m * 64 + ((((j * 2) ^ ((m & 7) << 4))) >> 1);
}
__device__ __forceinline__ int tb2_off(int m, int j) {     // 16 x 128 bf16
    return m * 128 + ((((j * 2) ^ ((m & 7) << 4))) >> 1);
}
__device__ __forceinline__ bf16x8 ld_tb(const unsigned short* tb, int m, int j0) {
    return as_bf16x8(*(const us8*)&tb[tb_off(m, j0)]);
}
__device__ __forceinline__ bf16x8 ld_tb2(const unsigned short* tb, int m, int j0) {
    return as_bf16x8(*(const us8*)&tb[tb2_off(m, j0)]);
}
// weight B-fragment from global (L1/L2-hot, 40KB working set per MLP)
__device__ __forceinline__ bf16x8 ld_frg(const ushort_t* __restrict__ FRG, int fid, int lane) {
    return as_bf16x8(*(const us8*)&FRG[(fid * 64 + lane) * 8]);
}

// ---------------- fused: coarse dst-histogram || weight frag pre-pack --------
__global__ __launch_bounds__(256) void prep_hist_k(
    const int* __restrict__ dst, int* __restrict__ chist,
    const float* __restrict__ iw1, const float* __restrict__ iw2,
    const float* __restrict__ iw3,
    const float* __restrict__ aw1, const float* __restrict__ aw2,
    const float* __restrict__ aw3,
    ushort_t* __restrict__ frg, int E, int cgrid)
{
    __shared__ int h[256];
    const int tid = threadIdx.x;
    if (blockIdx.x < cgrid) {
        h[tid] = 0;
        __syncthreads();
        const int base = blockIdx.x * ACH;
#pragma unroll
        for (int j = 0; j < 8; ++j) {
            const int e = base + j * 256 + tid;
            if (e < E) atomicAdd(&h[dst[e] >> BSH], 1);
        }
        __syncthreads();
        if (h[tid]) atomicAdd(&chist[tid], h[tid]);
    } else {
        const int g = (blockIdx.x - cgrid) * 256 + tid;     // 80*64 = 5120
        const int fid2 = g >> 6;
        if (fid2 >= 80) return;
        const int lane = g & 63;
        const int ln = lane & 15, hi = lane >> 4;
        const int set = fid2 / 40;
        const int fid = fid2 - set * 40;
        const float* w; int inF, s, t;
        if (fid < 16)      { w = set ? aw1 : iw1; inF = H;  s = fid >> 2;        t = fid & 3; }
        else if (fid < 24) { w = set ? aw2 : iw2; inF = HH; s = (fid - 16) >> 2; t = (fid - 16) & 3; }
        else               { w = set ? aw3 : iw3; inF = HH; s = (fid - 24) >> 3; t = (fid - 24) & 7; }
        const float* p = w + (size_t)(t * 16 + ln) * inF + (s * 32 + hi * 8);
        f32x4 a = *(const f32x4*)p;
        f32x4 b = *(const f32x4*)(p + 4);
        ushort_t* d = &frg[(size_t)(fid2 * 64 + lane) * 8];
        d[0] = bfbits(a[0]); d[1] = bfbits(a[1]); d[2] = bfbits(a[2]); d[3] = bfbits(a[3]);
        d[4] = bfbits(b[0]); d[5] = bfbits(b[1]); d[6] = bfbits(b[2]); d[7] = bfbits(b[3]);
    }
}

// single block: coarse-bucket exclusive scan -> cbase/ccur
__global__ __launch_bounds__(256) void cscan_k(
    const int* __restrict__ chist, int* __restrict__ cbase, int* __restrict__ ccur,
    int nb, int E)
{
    __shared__ int s[256];
    const int tid = threadIdx.x;
    const int v = (tid < nb) ? chist[tid] : 0;
    s[tid] = v;
    __syncthreads();
    for (int st = 1; st < 256; st <<= 1) {
        int t = (tid >= st) ? s[tid - st] : 0;
        __syncthreads();
        s[tid] += t;
        __syncthreads();
    }
    const int excl = s[tid] - v;
    if (tid < nb) { cbase[tid] = excl; ccur[tid] = excl; }
    if (tid == 0) cbase[nb] = E;
}

// coarse pass: bin edges by dst>>BSH; entry = (dloc<<18)|(src<<1)|r
__global__ __launch_bounds__(256) void coarse_bin_k(
    const int* __restrict__ src, const int* __restrict__ dst,
    const int* __restrict__ r,
    int* __restrict__ ccur, unsigned* __restrict__ ebuf, int E)
{
    __shared__ int hcnt[256];
    __shared__ int gbase[256];
    __shared__ int lcur[256];
    const int tid = threadIdx.x;
    hcnt[tid] = 0;
    __syncthreads();
    const int base = blockIdx.x * ACH;
    unsigned v[8]; int bk[8];
#pragma unroll
    for (int j = 0; j < 8; ++j) {
        const int e = base + j * 256 + tid;
        if (e < E) {
            const int d = dst[e];
            bk[j] = d >> BSH;
            v[j] = ((unsigned)(d & (BSZ - 1)) << 18) |
                   ((unsigned)src[e] << 1) | (unsigned)r[e];
            atomicAdd(&hcnt[bk[j]], 1);
        } else bk[j] = -1;
    }
    __syncthreads();
    const int c = hcnt[tid];
    gbase[tid] = (c > 0) ? atomicAdd(&ccur[tid], c) : 0;
    lcur[tid] = 0;
    __syncthreads();
#pragma unroll
    for (int j = 0; j < 8; ++j) {
        if (bk[j] >= 0) {
            const int loc = atomicAdd(&lcur[bk[j]], 1);
            ebuf[gbase[bk[j]] + loc] = v[j];
        }
    }
}

// ---------------- fused: fine_build || MLP pass 1 (2 tiles per wave) ---------
__global__ __launch_bounds__(512) void pass1_fine_k(
    const float* __restrict__ X,
    const ushort_t* __restrict__ FRG,
    const float* __restrict__ B1, const float* __restrict__ B2,
    const float* __restrict__ B3,
    ushort_t* __restrict__ invb, ushort_t* __restrict__ featb,
    const unsigned* __restrict__ ebuf, const int* __restrict__ cbase,
    int* __restrict__ offsets, int* __restrict__ packed,
    int N, int E, int NB, int ntiles)
{
    __shared__ __align__(16) unsigned short TBs[8 * 2 * 16 * 64];  // 32 KB
    const int tid = threadIdx.x;

    if (blockIdx.x < NB) {
        // ------- fine_build body (uses TBs as two int[512] arrays) ----------
        int* loff = (int*)TBs;
        int* lcur = loff + BSZ;
        const int b = blockIdx.x;
        const int lo = b << BSH;
        const int nn = min(BSZ, N - lo);
        const int rstart = cbase[b];
        const int rend   = cbase[b + 1];
        lcur[tid] = 0;
        __syncthreads();
        for (int i = rstart + tid; i < rend; i += BSZ)
            atomicAdd(&lcur[ebuf[i] >> 18], 1);
        __syncthreads();
        const int v = lcur[tid];
        loff[tid] = v;
        __syncthreads();
        for (int st = 1; st < BSZ; st <<= 1) {
            int t = (tid >= st) ? loff[tid - st] : 0;
            __syncthreads();
            loff[tid] += t;
            __syncthreads();
        }
        const int base = rstart + loff[tid] - v;     // exclusive prefix
        if (tid < nn) offsets[lo + tid] = base;
        if (b == NB - 1 && tid == 0) offsets[N] = E;
        __syncthreads();
        lcur[tid] = base;
        __syncthreads();
        for (int i = rstart + tid; i < rend; i += BSZ) {
            const unsigned w = ebuf[i];
            const int dloc = w >> 18;
            const int pos = atomicAdd(&lcur[dloc], 1);
            packed[pos] = (int)(((w & 0x3ffffu) >> 1) | ((w & 1u) << 31));
        }
        return;
    }

    // ------- MLP pass-1 body: 2 tiles (32 rows) per wave, shared frag loads --
    const int wv   = tid >> 6;
    const int lane = tid & 63;
    const int ln   = lane & 15;
    const int hi   = lane >> 4;

    const int gw = (blockIdx.x - NB) * 8 + wv;
    const int t0 = gw * 2;
    if (t0 >= ntiles) return;
    const bool hasB = (t0 + 1) < ntiles;
    const int node0A = t0 * 16;
    const int node0B = hasB ? (t0 + 1) * 16 : node0A;

    float b1r[4], b2r[4], b3r[8];
#pragma unroll
    for (int t = 0; t < 4; ++t) b1r[t] = B1[t * 16 + ln];
#pragma unroll
    for (int t = 0; t < 4; ++t) b2r[t] = B2[t * 16 + ln];
#pragma unroll
    for (int t = 0; t < 8; ++t) b3r[t] = B3[t * 16 + ln];

    unsigned short* tbA = &TBs[(wv * 2) * 16 * 64];
    unsigned short* tbB = tbA + 16 * 64;

    const size_t roA = (size_t)min(node0A + ln, N - 1) * H;
    const size_t roB = (size_t)min(node0B + ln, N - 1) * H;

    bf16x8 aA[4], aB[4];
#pragma unroll
    for (int s = 0; s < 4; ++s) {
        {
            f32x4 u = *(const f32x4*)(X + roA + s * 32 + hi * 8);
            f32x4 v = *(const f32x4*)(X + roA + s * 32 + hi * 8 + 4);
            bf16x8 f;
            f[0] = (__bf16)u[0]; f[1] = (__bf16)u[1]; f[2] = (__bf16)u[2]; f[3] = (__bf16)u[3];
            f[4] = (__bf16)v[0]; f[5] = (__bf16)v[1]; f[6] = (__bf16)v[2]; f[7] = (__bf16)v[3];
            aA[s] = f;
            *(us8*)(featb + roA + s * 32 + hi * 8) = __builtin_bit_cast(us8, f);
        }
        {
            f32x4 u = *(const f32x4*)(X + roB + s * 32 + hi * 8);
            f32x4 v = *(const f32x4*)(X + roB + s * 32 + hi * 8 + 4);
            bf16x8 f;
            f[0] = (__bf16)u[0]; f[1] = (__bf16)u[1]; f[2] = (__bf16)u[2]; f[3] = (__bf16)u[3];
            f[4] = (__bf16)v[0]; f[5] = (__bf16)v[1]; f[6] = (__bf16)v[2]; f[7] = (__bf16)v[3];
            aB[s] = f;
            if (hasB) *(us8*)(featb + roB + s * 32 + hi * 8) = __builtin_bit_cast(us8, f);
        }
    }

    // layer 1
#pragma unroll 2
    for (int t = 0; t < 4; ++t) {
        f32x4 accA = {0.f, 0.f, 0.f, 0.f}, accB = {0.f, 0.f, 0.f, 0.f};
#pragma unroll
        for (int s = 0; s < 4; ++s) {
            const bf16x8 f = ld_frg(FRG, s * 4 + t, lane);
            accA = __builtin_amdgcn_mfma_f32_16x16x32_bf16(aA[s], f, accA, 0, 0, 0);
            accB = __builtin_amdgcn_mfma_f32_16x16x32_bf16(aB[s], f, accB, 0, 0, 0);
        }
#pragma unroll
        for (int q = 0; q < 4; ++q) {
            float yA = accA[q] + b1r[t];
            yA = (yA >= 0.f) ? yA : 0.01f * yA;
            tbA[tb_off(hi * 4 + q, t * 16 + ln)] = bfbits(yA);
            float yB = accB[q] + b1r[t];
            yB = (yB >= 0.f) ? yB : 0.01f * yB;
            tbB[tb_off(hi * 4 + q, t * 16 + ln)] = bfbits(yB);
        }
    }

    // layer 2
    bf16x8 a2A[2], a2B[2];
#pragma unroll
    for (int s = 0; s < 2; ++s) {
        a2A[s] = ld_tb(tbA, ln, s * 32 + hi * 8);
        a2B[s] = ld_tb(tbB, ln, s * 32 + hi * 8);
    }
#pragma unroll 2
    for (int t = 0; t < 4; ++t) {
        f32x4 accA = {0.f, 0.f, 0.f, 0.f}, accB = {0.f, 0.f, 0.f, 0.f};
#pragma unroll
        for (int s = 0; s < 2; ++s) {
            const bf16x8 f = ld_frg(FRG, 16 + s * 4 + t, lane);
            accA = __builtin_amdgcn_mfma_f32_16x16x32_bf16(a2A[s], f, accA, 0, 0, 0);
            accB = __builtin_amdgcn_mfma_f32_16x16x32_bf16(a2B[s], f, accB, 0, 0, 0);
        }
#pragma unroll
        for (int q = 0; q < 4; ++q) {
            float yA = accA[q] + b2r[t];
            yA = (yA >= 0.f) ? yA : 0.01f * yA;
            tbA[tb_off(hi * 4 + q, t * 16 + ln)] = bfbits(yA);
            float yB = accB[q] + b2r[t];
            yB = (yB >= 0.f) ? yB : 0.01f * yB;
            tbB[tb_off(hi * 4 + q, t * 16 + ln)] = bfbits(yB);
        }
    }

    // layer 3 -> bf16 invb, staged through LDS for coalesced 16B stores
    bf16x8 a3A[2], a3B[2];
#pragma unroll
    for (int s = 0; s < 2; ++s) {
        a3A[s] = ld_tb(tbA, ln, s * 32 + hi * 8);
        a3B[s] = ld_tb(tbB, ln, s * 32 + hi * 8);
    }
#pragma unroll
    for (int half = 0; half < 2; ++half) {
#pragma unroll 2
        for (int t2 = 0; t2 < 4; ++t2) {
            const int t = half * 4 + t2;
            f32x4 accA = {0.f, 0.f, 0.f, 0.f}, accB = {0.f, 0.f, 0.f, 0.f};
#pragma unroll
            for (int s = 0; s < 2; ++s) {
                const bf16x8 f = ld_frg(FRG, 24 + s * 8 + t, lane);
                accA = __builtin_amdgcn_mfma_f32_16x16x32_bf16(a3A[s], f, accA, 0, 0, 0);
                accB = __builtin_amdgcn_mfma_f32_16x16x32_bf16(a3B[s], f, accB, 0, 0, 0);
            }
#pragma unroll
            for (int q = 0; q < 4; ++q) {
                tbA[tb_off(hi * 4 + q, t2 * 16 + ln)] = bfbits(accA[q] + b3r[t]);
                tbB[tb_off(hi * 4 + q, t2 * 16 + ln)] = bfbits(accB[q] + b3r[t]);
            }
        }
        const int rr = lane >> 2, c0 = (lane & 3) * 16;
        if (node0A + rr < N) {
            us8 w0 = __builtin_bit_cast(us8, ld_tb(tbA, rr, c0));
            us8 w1 = __builtin_bit_cast(us8, ld_tb(tbA, rr, c0 + 8));
            ushort_t* op = invb + (size_t)(node0A + rr) * H + half * 64 + c0;
            *(us8*)op = w0;
            *(us8*)(op + 8) = w1;
        }
        if (hasB && node0B + rr < N) {
            us8 w0 = __builtin_bit_cast(us8, ld_tb(tbB, rr, c0));
            us8 w1 = __builtin_bit_cast(us8, ld_tb(tbB, rr, c0 + 8));
            ushort_t* op = invb + (size_t)(node0B + rr) * H + half * 64 + c0;
            *(us8*)op = w0;
            *(us8*)(op + 8) = w1;
        }
    }
}

// ---------------- fused pass 4+5, 2 tiles per wave ----------------------------
// res = mlp_and(neigh); out = inv ? mlp_inv(res) : res. bf16(res) kept in the
// per-wave 16x128 LDS buffers between phases.
__global__ __launch_bounds__(256) void mlp45_k(
    const ushort_t* __restrict__ Xb,          // neighb, bf16
    const ushort_t* __restrict__ FRGa,        // and frags
    const ushort_t* __restrict__ FRGi,        // inv frags
    const float* __restrict__ A1, const float* __restrict__ A2,
    const float* __restrict__ A3,
    const float* __restrict__ I1, const float* __restrict__ I2,
    const float* __restrict__ I3,
    float* __restrict__ OUT,
    const int* __restrict__ invp,
    int nrows, int ntiles)
{
    __shared__ __align__(16) unsigned short TB2[4 * 2 * 16 * 128];  // 32 KB
    const int tid  = threadIdx.x;
    const int wv   = tid >> 6;
    const int lane = tid & 63;
    const int ln   = lane & 15;
    const int hi   = lane >> 4;

    const int gw = blockIdx.x * 4 + wv;
    const int t0 = gw * 2;
    if (t0 >= ntiles) return;
    const bool hasB = (t0 + 1) < ntiles;
    const int node0A = t0 * 16;
    const int node0B = hasB ? (t0 + 1) * 16 : node0A;

    unsigned short* tbA = &TB2[(wv * 2) * 16 * 128];
    unsigned short* tbB = tbA + 16 * 128;

    int iqA[4], iqB[4];
#pragma unroll
    for (int q = 0; q < 4; ++q) {
        const int rA = node0A + hi * 4 + q;
        const int rB = node0B + hi * 4 + q;
        iqA[q] = (rA < nrows) ? invp[rA] : 1;
        iqB[q] = (rB < nrows) ? invp[rB] : 1;
    }

    // ---- phase A: mlp_and ----
    {
        float b1r[4], b2r[4], b3r[8];
#pragma unroll
        for (int t = 0; t < 4; ++t) b1r[t] = A1[t * 16 + ln];
#pragma unroll
        for (int t = 0; t < 4; ++t) b2r[t] = A2[t * 16 + ln];
#pragma unroll
        for (int t = 0; t < 8; ++t) b3r[t] = A3[t * 16 + ln];

        const size_t roA = (size_t)min(node0A + ln, nrows - 1) * H;
        const size_t roB = (size_t)min(node0B + ln, nrows - 1) * H;
        bf16x8 aA[4], aB[4];
#pragma unroll
        for (int s = 0; s < 4; ++s) {
            aA[s] = as_bf16x8(*(const us8*)(Xb + roA + s * 32 + hi * 8));
            aB[s] = as_bf16x8(*(const us8*)(Xb + roB + s * 32 + hi * 8));
        }

#pragma unroll 2
        for (int t = 0; t < 4; ++t) {
            f32x4 accA = {0.f, 0.f, 0.f, 0.f}, accB = {0.f, 0.f, 0.f, 0.f};
#pragma unroll
            for (int s = 0; s < 4; ++s) {
                const bf16x8 f = ld_frg(FRGa, s * 4 + t, lane);
                accA = __builtin_amdgcn_mfma_f32_16x16x32_bf16(aA[s], f, accA, 0, 0, 0);
                accB = __builtin_amdgcn_mfma_f32_16x16x32_bf16(aB[s], f, accB, 0, 0, 0);
            }
#pragma unroll
            for (int q = 0; q < 4; ++q) {
                float yA = accA[q] + b1r[t];
                yA = (yA >= 0.f) ? yA : 0.01f * yA;
                tbA[tb2_off(hi * 4 + q, t * 16 + ln)] = bfbits(yA);
                float yB = accB[q] + b1r[t];
                yB = (yB >= 0.f) ? yB : 0.01f * yB;
                tbB[tb2_off(hi * 4 + q, t * 16 + ln)] = bfbits(yB);
            }
        }

        bf16x8 a2A[2], a2B[2];
#pragma unroll
        for (int s = 0; s < 2; ++s) {
            a2A[s] = ld_tb2(tbA, ln, s * 32 + hi * 8);
            a2B[s] = ld_tb2(tbB, ln, s * 32 + hi * 8);
        }
#pragma unroll 2
        for (int t = 0; t < 4; ++t) {
            f32x4 accA = {0.f, 0.f, 0.f, 0.f}, accB = {0.f, 0.f, 0.f, 0.f};
#pragma unroll
            for (int s = 0; s < 2; ++s) {
                const bf16x8 f = ld_frg(FRGa, 16 + s * 4 + t, lane);
                accA = __builtin_amdgcn_mfma_f32_16x16x32_bf16(a2A[s], f, accA, 0, 0, 0);
                accB = __builtin_amdgcn_mfma_f32_16x16x32_bf16(a2B[s], f, accB, 0, 0, 0);
            }
#pragma unroll
            for (int q = 0; q < 4; ++q) {
                float yA = accA[q] + b2r[t];
                yA = (yA >= 0.f) ? yA : 0.01f * yA;
                tbA[tb2_off(hi * 4 + q, t * 16 + ln)] = bfbits(yA);
                float yB = accB[q] + b2r[t];
                yB = (yB >= 0.f) ? yB : 0.01f * yB;
                tbB[tb2_off(hi * 4 + q, t * 16 + ln)] = bfbits(yB);
            }
        }

        bf16x8 a3A[2], a3B[2];
#pragma unroll
        for (int s = 0; s < 2; ++s) {
            a3A[s] = ld_tb2(tbA, ln, s * 32 + hi * 8);
            a3B[s] = ld_tb2(tbB, ln, s * 32 + hi * 8);
        }
#pragma unroll 2
        for (int t = 0; t < 8; ++t) {
            f32x4 accA = {0.f, 0.f, 0.f, 0.f}, accB = {0.f, 0.f, 0.f, 0.f};
#pragma unroll
            for (int s = 0; s < 2; ++s) {
                const bf16x8 f = ld_frg(FRGa, 24 + s * 8 + t, lane);
                accA = __builtin_amdgcn_mfma_f32_16x16x32_bf16(a3A[s], f, accA, 0, 0, 0);
                accB = __builtin_amdgcn_mfma_f32_16x16x32_bf16(a3B[s], f, accB, 0, 0, 0);
            }
#pragma unroll
            for (int q = 0; q < 4; ++q) {
                const float yA = accA[q] + b3r[t];
                tbA[tb2_off(hi * 4 + q, t * 16 + ln)] = bfbits(yA);
                const int rA = node0A + hi * 4 + q;
                if (rA < nrows && !iqA[q])
                    OUT[(size_t)rA * H + t * 16 + ln] = yA;
                const float yB = accB[q] + b3r[t];
                tbB[tb2_off(hi * 4 + q, t * 16 + ln)] = bfbits(yB);
                const int rB = node0B + hi * 4 + q;
                if (hasB && rB < nrows && !iqB[q])
                    OUT[(size_t)rB * H + t * 16 + ln] = yB;
            }
        }
    }

    // ---- phase B: mlp_inv(res) for inv rows ----
    {
        float b1r[4], b2r[4], b3r[8];
#pragma unroll
        for (int t = 0; t < 4; ++t) b1r[t] = I1[t * 16 + ln];
#pragma unroll
        for (int t = 0; t < 4; ++t) b2r[t] = I2[t * 16 + ln];
#pragma unroll
        for (int t = 0; t < 8; ++t) b3r[t] = I3[t * 16 + ln];

        bf16x8 aA[4], aB[4];
#pragma unroll
        for (int s = 0; s < 4; ++s) {
            aA[s] = ld_tb2(tbA, ln, s * 32 + hi * 8);   // reads drain before writes
            aB[s] = ld_tb2(tbB, ln, s * 32 + hi * 8);
        }

#pragma unroll 2
        for (int t = 0; t < 4; ++t) {
            f32x4 accA = {0.f, 0.f, 0.f, 0.f}, accB = {0.f, 0.f, 0.f, 0.f};
#pragma unroll
            for (int s = 0; s < 4; ++s) {
                const bf16x8 f = ld_frg(FRGi, s * 4 + t, lane);
                accA = __builtin_amdgcn_mfma_f32_16x16x32_bf16(aA[s], f, accA, 0, 0, 0);
                accB = __builtin_amdgcn_mfma_f32_16x16x32_bf16(aB[s], f, accB, 0, 0, 0);
            }
#pragma unroll
            for (int q = 0; q < 4; ++q) {
                float yA = accA[q] + b1r[t];
                yA = (yA >= 0.f) ? yA : 0.01f * yA;
                tbA[tb2_off(hi * 4 + q, t * 16 + ln)] = bfbits(yA);
                float yB = accB[q] + b1r[t];
                yB = (yB >= 0.f) ? yB : 0.01f * yB;
                tbB[tb2_off(hi * 4 + q, t * 16 + ln)] = bfbits(yB);
            }
        }

        bf16x8 a2A[2], a2B[2];
#pragma unroll
        for (int s = 0; s < 2; ++s) {
            a2A[s] = ld_tb2(tbA, ln, s * 32 + hi * 8);
            a2B[s] = ld_tb2(tbB, ln, s * 32 + hi * 8);
        }
#pragma unroll 2
        for (int t = 0; t < 4; ++t) {
            f32x4 accA = {0.f, 0.f, 0.f, 0.f}, accB = {0.f, 0.f, 0.f, 0.f};
#pragma unroll
            for (int s = 0; s < 2; ++s) {
                const bf16x8 f = ld_frg(FRGi, 16 + s * 4 + t, lane);
                accA = __builtin_amdgcn_mfma_f32_16x16x32_bf16(a2A[s], f, accA, 0, 0, 0);
                accB = __builtin_amdgcn_mfma_f32_16x16x32_bf16(a2B[s], f, accB, 0, 0, 0);
            }
#pragma unroll
            for (int q = 0; q < 4; ++q) {
                float yA = accA[q] + b2r[t];
                yA = (yA >= 0.f) ? yA : 0.01f * yA;
                tbA[tb2_off(hi * 4 + q, t * 16 + ln)] = bfbits(yA);
                float yB = accB[q] + b2r[t];
                yB = (yB >= 0.f) ? yB : 0.01f * yB;
                tbB[tb2_off(hi * 4 + q, t * 16 + ln)] = bfbits(yB);
            }
        }

        bf16x8 a3A[2], a3B[2];
#pragma unroll
        for (int s = 0; s < 2; ++s) {
            a3A[s] = ld_tb2(tbA, ln, s * 32 + hi * 8);
            a3B[s] = ld_tb2(tbB, ln, s * 32 + hi * 8);
        }
#pragma unroll 2
        for (int t = 0; t < 8; ++t) {
            f32x4 accA = {0.f, 0.f, 0.f, 0.f}, accB = {0.f, 0.f, 0.f, 0.f};
#pragma unroll
            for (int s = 0; s < 2; ++s) {
                const bf16x8 f = ld_frg(FRGi, 24 + s * 8 + t, lane);
                accA = __builtin_amdgcn_mfma_f32_16x16x32_bf16(a3A[s], f, accA, 0, 0, 0);
                accB = __builtin_amdgcn_mfma_f32_16x16x32_bf16(a3B[s], f, accB, 0, 0, 0);
            }
#pragma unroll
            for (int q = 0; q < 4; ++q) {
                const int rA = node0A + hi * 4 + q;
                if (rA < nrows && iqA[q])
                    OUT[(size_t)rA * H + t * 16 + ln] = accA[q] + b3r[t];
                const int rB = node0B + hi * 4 + q;
                if (hasB && rB < nrows && iqB[q])
                    OUT[(size_t)rB * H + t * 16 + ln] = accB[q] + b3r[t];
            }
        }
    }
}

// one wave per node: 4 rows x 16 lanes x 16B, 16 rows in flight; f32 accum;
// shfl_xor(16,32) combine; bf16 mean out. deg = offsets diff.
__global__ __launch_bounds__(256) void gather_mean_k(
    const ushort_t* __restrict__ featb, const ushort_t* __restrict__ invb,
    const int* __restrict__ offsets,
    const int* __restrict__ packed, ushort_t* __restrict__ neighb, int N)
{
    const int wv = threadIdx.x >> 6, lane = threadIdx.x & 63;
    const int n = blockIdx.x * 4 + wv;
    if (n >= N) return;
    const int start = offsets[n];
    const int d = offsets[n + 1] - start;
    const int q4 = lane >> 4;                    // row-in-group 0..3
    const size_t co = (size_t)(lane & 15) * 8;   // col base
    float a[8] = {0.f, 0.f, 0.f, 0.f, 0.f, 0.f, 0.f, 0.f};
    int k = 0;
    for (; k + 15 < d; k += 16) {
        const int p0 = packed[start + k + q4];
        const int p1 = packed[start + k + 4 + q4];
        const int p2 = packed[start + k + 8 + q4];
        const int p3 = packed[start + k + 12 + q4];
        const ushort_t* t0 = (p0 < 0) ? invb : featb;
        const ushort_t* t1 = (p1 < 0) ? invb : featb;
        const ushort_t* t2 = (p2 < 0) ? invb : featb;
        const ushort_t* t3 = (p3 < 0) ? invb : featb;
        const us8 u0 = *(const us8*)(t0 + (size_t)(p0 & 0x7fffffff) * H + co);
        const us8 u1 = *(const us8*)(t1 + (size_t)(p1 & 0x7fffffff) * H + co);
        const us8 u2 = *(const us8*)(t2 + (size_t)(p2 & 0x7fffffff) * H + co);
        const us8 u3 = *(const us8*)(t3 + (size_t)(p3 & 0x7fffffff) * H + co);
#pragma unroll
        for (int i = 0; i < 8; ++i) a[i] += (bfl(u0[i]) + bfl(u1[i])) + (bfl(u2[i]) + bfl(u3[i]));
    }
    for (; k + 7 < d; k += 8) {
        const int pA = packed[start + k + q4];
        const int pB = packed[start + k + 4 + q4];
        const ushort_t* tA = (pA < 0) ? invb : featb;
        const ushort_t* tB = (pB < 0) ? invb : featb;
        const us8 uA = *(const us8*)(tA + (size_t)(pA & 0x7fffffff) * H + co);
        const us8 uB = *(const us8*)(tB + (size_t)(pB & 0x7fffffff) * H + co);
#pragma unroll
        for (int i = 0; i < 8; ++i) a[i] += bfl(uA[i]) + bfl(uB[i]);
    }
    if (k + 3 < d) {
        const int p = packed[start + k + q4];
        const ushort_t* t = (p < 0) ? invb : featb;
        const us8 u = *(const us8*)(t + (size_t)(p & 0x7fffffff) * H + co);
#pragma unroll
        for (int i = 0; i < 8; ++i) a[i] += bfl(u[i]);
        k += 4;
    }
    const int rem = d - k;
    if (q4 < rem) {
        const int p = packed[start + k + q4];
        const ushort_t* t = (p < 0) ? invb : featb;
        const us8 u = *(const us8*)(t + (size_t)(p & 0x7fffffff) * H + co);
#pragma unroll
        for (int i = 0; i < 8; ++i) a[i] += bfl(u[i]);
    }
#pragma unroll
    for (int i = 0; i < 8; ++i) {
        a[i] += __shfl_xor(a[i], 16);
        a[i] += __shfl_xor(a[i], 32);
    }
    if (q4 == 0) {
        const float scl = 1.0f / (float)max(d, 1);
        us8 o;
#pragma unroll
        for (int i = 0; i < 8; ++i) o[i] = bfbits(a[i] * scl);
        *(us8*)(neighb + (size_t)n * H + co) = o;
    }
}

extern "C" void kernel_launch(void* const* d_in, const int* in_sizes, int n_in,
                              void* d_out, int out_size, void* d_ws, size_t ws_size,
                              hipStream_t stream) {
    const float* feat = (const float*)d_in[0];
    const int*   src  = (const int*)d_in[1];
    const int*   dst  = (const int*)d_in[2];
    const int*   r    = (const int*)d_in[3];
    const int*   inv  = (const int*)d_in[4];
    const float* iw1 = (const float*)d_in[5],  *ib1 = (const float*)d_in[6];
    const float* iw2 = (const float*)d_in[7],  *ib2 = (const float*)d_in[8];
    const float* iw3 = (const float*)d_in[9],  *ib3 = (const float*)d_in[10];
    const float* aw1 = (const float*)d_in[11], *ab1 = (const float*)d_in[12];
    const float* aw2 = (const float*)d_in[13], *ab2 = (const float*)d_in[14];
    const float* aw3 = (const float*)d_in[15], *ab3 = (const float*)d_in[16];

    const int N = in_sizes[4];   // inv is [N]
    const int E = in_sizes[1];   // src is [E]

    ushort_t* featb  = (ushort_t*)d_ws;             // N*H bf16
    ushort_t* invb   = featb + (size_t)N * H;       // N*H bf16
    ushort_t* neighb = invb + (size_t)N * H;        // N*H bf16
    int* offsets = (int*)(neighb + (size_t)N * H);  // N+1
    unsigned* ebuf = (unsigned*)(offsets + (N + 1));
    int* packed  = (int*)(ebuf + E);
    ushort_t* frg = (ushort_t*)(packed + E);        // 80 frags x 512 us = 80 KB
    int* chist   = (int*)(frg + 80 * 512);
    int* cbase   = chist + 256;                     // 257
    int* ccur    = cbase + 257;

    ushort_t* frg_inv = frg;
    ushort_t* frg_and = frg + 40 * 512;

    const int ntiles = (N + 15) / 16;
    const int NB     = (N + BSZ - 1) / BSZ;         // coarse buckets (<=256)
    const int cgrid  = (E + ACH - 1) / ACH;
    const int gp1    = (ntiles + 15) / 16;          // pass1: 8 waves x 2 tiles
    const int g45    = (ntiles + 7) / 8;            // mlp45: 4 waves x 2 tiles

    hipMemsetAsync(chist, 0, 256 * sizeof(int), stream);

    // 1) coarse histogram || weight frag pre-pack
    prep_hist_k<<<cgrid + 20, 256, 0, stream>>>(dst, chist, iw1, iw2, iw3,
                                                aw1, aw2, aw3, frg, E, cgrid);
    // 2) coarse-bucket scan
    cscan_k<<<1, 256, 0, stream>>>(chist, cbase, ccur, NB, E);
    // 3) coarse bin pass
    coarse_bin_k<<<cgrid, 256, 0, stream>>>(src, dst, r, ccur, ebuf, E);
    // 4) fine CSR build || pass1 (invb = bf16(mlp_inv(feat)), featb = bf16(feat))
    pass1_fine_k<<<NB + gp1, 512, 0, stream>>>(feat, frg_inv, ib1, ib2, ib3,
                                               invb, featb, ebuf, cbase,
                                               offsets, packed, N, E, NB, ntiles);
    // 5) neighb = bf16(mean of messages by dst)
    gather_mean_k<<<(N + 3) / 4, 256, 0, stream>>>(featb, invb, offsets,
                                                   packed, neighb, N);
    // 6) fused: res = mlp_and(neighb); out = inv ? mlp_inv(res) : res
    mlp45_k<<<g45, 256, 0, stream>>>(neighb, frg_and, frg_inv,
                                     ab1, ab2, ab3, ib1, ib2, ib3,
                                     (float*)d_out, inv, N, ntiles);
}

// Round 11
// 143.278 us; speedup vs baseline: 3.1045x; 1.0160x over previous
//
#include <hip/hip_runtime.h>

// FuncConv: out = select(inv, mlp_inv(res), res); res = mlp_and(mean_dst(msg));
// msg = select(r, mlp_inv(feat[src]), feat[src]).
// R10: R9's M-blocking helped mlp45 (grid stayed 782) but not pass1 (grid
// halved to 587 -> 2.3 blocks/CU, Occupancy 21%). Fix: pass1 MLP now
// 256-thr/4-wave blocks x 2 tiles/wave -> grid 978, 16KB LDS; fine_build
// body reworked for 256 threads (pair-per-thread scan over 512 slots).
//
// ws: featb[N*H bf16] invb[N*H bf16] neighb[N*H bf16]
//     offsets[N+1] ebuf[E] packed[E] frg[80*512 us] chist[256] cbase[257] ccur[256]

#define H 128
#define HH 64
#define BSH 9     // log2 nodes per coarse bucket
#define BSZ 512   // nodes per coarse bucket
#define ACH 2048  // edges per coarse block

typedef float f32x4 __attribute__((ext_vector_type(4)));
typedef __bf16 bf16x8 __attribute__((ext_vector_type(8)));
typedef unsigned short us8 __attribute__((ext_vector_type(8)));
typedef unsigned short ushort_t;

__device__ __forceinline__ unsigned short bfbits(float f) {
    __bf16 h = (__bf16)f;                       // RNE convert
    return __builtin_bit_cast(unsigned short, h);
}
__device__ __forceinline__ bf16x8 as_bf16x8(us8 v) {
    return __builtin_bit_cast(bf16x8, v);
}
__device__ __forceinline__ float bfl(unsigned short u) {
    return __builtin_bit_cast(float, ((unsigned)u) << 16);
}

// per-wave transpose buffers, XOR-swizzled (byte ^= (row&7)<<4; 16B groups)
__device__ __forceinline__ int tb_off(int m, int j) {      // 16 x 64 bf16
    return m * 64 + ((((j * 2) ^ ((m & 7) << 4))) >> 1);
}
__device__ __forceinline__ int tb2_off(int m, int j) {     // 16 x 128 bf16
    return m * 128 + ((((j * 2) ^ ((m & 7) << 4))) >> 1);
}
__device__ __forceinline__ bf16x8 ld_tb(const unsigned short* tb, int m, int j0) {
    return as_bf16x8(*(const us8*)&tb[tb_off(m, j0)]);
}
__device__ __forceinline__ bf16x8 ld_tb2(const unsigned short* tb, int m, int j0) {
    return as_bf16x8(*(const us8*)&tb[tb2_off(m, j0)]);
}
// weight B-fragment from global (L1/L2-hot, 40KB working set per MLP)
__device__ __forceinline__ bf16x8 ld_frg(const ushort_t* __restrict__ FRG, int fid, int lane) {
    return as_bf16x8(*(const us8*)&FRG[(fid * 64 + lane) * 8]);
}

// ---------------- fused: coarse dst-histogram || weight frag pre-pack --------
__global__ __launch_bounds__(256) void prep_hist_k(
    const int* __restrict__ dst, int* __restrict__ chist,
    const float* __restrict__ iw1, const float* __restrict__ iw2,
    const float* __restrict__ iw3,
    const float* __restrict__ aw1, const float* __restrict__ aw2,
    const float* __restrict__ aw3,
    ushort_t* __restrict__ frg, int E, int cgrid)
{
    __shared__ int h[256];
    const int tid = threadIdx.x;
    if (blockIdx.x < cgrid) {
        h[tid] = 0;
        __syncthreads();
        const int base = blockIdx.x * ACH;
#pragma unroll
        for (int j = 0; j < 8; ++j) {
            const int e = base + j * 256 + tid;
            if (e < E) atomicAdd(&h[dst[e] >> BSH], 1);
        }
        __syncthreads();
        if (h[tid]) atomicAdd(&chist[tid], h[tid]);
    } else {
        const int g = (blockIdx.x - cgrid) * 256 + tid;     // 80*64 = 5120
        const int fid2 = g >> 6;
        if (fid2 >= 80) return;
        const int lane = g & 63;
        const int ln = lane & 15, hi = lane >> 4;
        const int set = fid2 / 40;
        const int fid = fid2 - set * 40;
        const float* w; int inF, s, t;
        if (fid < 16)      { w = set ? aw1 : iw1; inF = H;  s = fid >> 2;        t = fid & 3; }
        else if (fid < 24) { w = set ? aw2 : iw2; inF = HH; s = (fid - 16) >> 2; t = (fid - 16) & 3; }
        else               { w = set ? aw3 : iw3; inF = HH; s = (fid - 24) >> 3; t = (fid - 24) & 7; }
        const float* p = w + (size_t)(t * 16 + ln) * inF + (s * 32 + hi * 8);
        f32x4 a = *(const f32x4*)p;
        f32x4 b = *(const f32x4*)(p + 4);
        ushort_t* d = &frg[(size_t)(fid2 * 64 + lane) * 8];
        d[0] = bfbits(a[0]); d[1] = bfbits(a[1]); d[2] = bfbits(a[2]); d[3] = bfbits(a[3]);
        d[4] = bfbits(b[0]); d[5] = bfbits(b[1]); d[6] = bfbits(b[2]); d[7] = bfbits(b[3]);
    }
}

// single block: coarse-bucket exclusive scan -> cbase/ccur
__global__ __launch_bounds__(256) void cscan_k(
    const int* __restrict__ chist, int* __restrict__ cbase, int* __restrict__ ccur,
    int nb, int E)
{
    __shared__ int s[256];
    const int tid = threadIdx.x;
    const int v = (tid < nb) ? chist[tid] : 0;
    s[tid] = v;
    __syncthreads();
    for (int st = 1; st < 256; st <<= 1) {
        int t = (tid >= st) ? s[tid - st] : 0;
        __syncthreads();
        s[tid] += t;
        __syncthreads();
    }
    const int excl = s[tid] - v;
    if (tid < nb) { cbase[tid] = excl; ccur[tid] = excl; }
    if (tid == 0) cbase[nb] = E;
}

// coarse pass: bin edges by dst>>BSH; entry = (dloc<<18)|(src<<1)|r
__global__ __launch_bounds__(256) void coarse_bin_k(
    const int* __restrict__ src, const int* __restrict__ dst,
    const int* __restrict__ r,
    int* __restrict__ ccur, unsigned* __restrict__ ebuf, int E)
{
    __shared__ int hcnt[256];
    __shared__ int gbase[256];
    __shared__ int lcur[256];
    const int tid = threadIdx.x;
    hcnt[tid] = 0;
    __syncthreads();
    const int base = blockIdx.x * ACH;
    unsigned v[8]; int bk[8];
#pragma unroll
    for (int j = 0; j < 8; ++j) {
        const int e = base + j * 256 + tid;
        if (e < E) {
            const int d = dst[e];
            bk[j] = d >> BSH;
            v[j] = ((unsigned)(d & (BSZ - 1)) << 18) |
                   ((unsigned)src[e] << 1) | (unsigned)r[e];
            atomicAdd(&hcnt[bk[j]], 1);
        } else bk[j] = -1;
    }
    __syncthreads();
    const int c = hcnt[tid];
    gbase[tid] = (c > 0) ? atomicAdd(&ccur[tid], c) : 0;
    lcur[tid] = 0;
    __syncthreads();
#pragma unroll
    for (int j = 0; j < 8; ++j) {
        if (bk[j] >= 0) {
            const int loc = atomicAdd(&lcur[bk[j]], 1);
            ebuf[gbase[bk[j]] + loc] = v[j];
        }
    }
}

// ---------------- fused: fine_build || MLP pass 1 -----------------------------
// 256 threads. blocks [0,NB): per 512-node bucket CSR build (pair-per-thread
// scan). blocks [NB,..): pass1 MLP, 4 waves x 2 tiles, shared frag loads.
__global__ __launch_bounds__(256) void pass1_fine_k(
    const float* __restrict__ X,
    const ushort_t* __restrict__ FRG,
    const float* __restrict__ B1, const float* __restrict__ B2,
    const float* __restrict__ B3,
    ushort_t* __restrict__ invb, ushort_t* __restrict__ featb,
    const unsigned* __restrict__ ebuf, const int* __restrict__ cbase,
    int* __restrict__ offsets, int* __restrict__ packed,
    int N, int E, int NB, int ntiles)
{
    __shared__ __align__(16) unsigned short TBs[4 * 2 * 16 * 64];  // 16 KB
    const int tid = threadIdx.x;

    if (blockIdx.x < NB) {
        // ------- fine_build body, 256 threads over 512 bucket slots ----------
        int* lcur = (int*)TBs;            // 512 ints
        int* ps   = lcur + BSZ;           // 256 ints
        const int b = blockIdx.x;
        const int lo = b << BSH;
        const int nn = min(BSZ, N - lo);
        const int rstart = cbase[b];
        const int rend   = cbase[b + 1];
        lcur[tid] = 0; lcur[tid + 256] = 0;
        __syncthreads();
        for (int i = rstart + tid; i < rend; i += 256)
            atomicAdd(&lcur[ebuf[i] >> 18], 1);
        __syncthreads();
        const int v0 = lcur[2 * tid];
        const int v1 = lcur[2 * tid + 1];
        const int psum = v0 + v1;
        ps[tid] = psum;
        __syncthreads();
        for (int st = 1; st < 256; st <<= 1) {
            int t = (tid >= st) ? ps[tid - st] : 0;
            __syncthreads();
            ps[tid] += t;
            __syncthreads();
        }
        const int e0 = rstart + ps[tid] - psum;     // exclusive prefix
        const int e1 = e0 + v0;
        if (2 * tid < nn)     offsets[lo + 2 * tid] = e0;
        if (2 * tid + 1 < nn) offsets[lo + 2 * tid + 1] = e1;
        if (b == NB - 1 && tid == 0) offsets[N] = E;
        __syncthreads();
        lcur[2 * tid] = e0;
        lcur[2 * tid + 1] = e1;
        __syncthreads();
        for (int i = rstart + tid; i < rend; i += 256) {
            const unsigned w = ebuf[i];
            const int dloc = w >> 18;
            const int pos = atomicAdd(&lcur[dloc], 1);
            packed[pos] = (int)(((w & 0x3ffffu) >> 1) | ((w & 1u) << 31));
        }
        return;
    }

    // ------- MLP pass-1 body: 4 waves x 2 tiles, shared frag loads -----------
    const int wv   = tid >> 6;
    const int lane = tid & 63;
    const int ln   = lane & 15;
    const int hi   = lane >> 4;

    const int gw = (blockIdx.x - NB) * 4 + wv;
    const int t0 = gw * 2;
    if (t0 >= ntiles) return;
    const bool hasB = (t0 + 1) < ntiles;
    const int node0A = t0 * 16;
    const int node0B = hasB ? (t0 + 1) * 16 : node0A;

    float b1r[4], b2r[4], b3r[8];
#pragma unroll
    for (int t = 0; t < 4; ++t) b1r[t] = B1[t * 16 + ln];
#pragma unroll
    for (int t = 0; t < 4; ++t) b2r[t] = B2[t * 16 + ln];
#pragma unroll
    for (int t = 0; t < 8; ++t) b3r[t] = B3[t * 16 + ln];

    unsigned short* tbA = &TBs[(wv * 2) * 16 * 64];
    unsigned short* tbB = tbA + 16 * 64;

    const size_t roA = (size_t)min(node0A + ln, N - 1) * H;
    const size_t roB = (size_t)min(node0B + ln, N - 1) * H;

    bf16x8 aA[4], aB[4];
#pragma unroll
    for (int s = 0; s < 4; ++s) {
        {
            f32x4 u = *(const f32x4*)(X + roA + s * 32 + hi * 8);
            f32x4 v = *(const f32x4*)(X + roA + s * 32 + hi * 8 + 4);
            bf16x8 f;
            f[0] = (__bf16)u[0]; f[1] = (__bf16)u[1]; f[2] = (__bf16)u[2]; f[3] = (__bf16)u[3];
            f[4] = (__bf16)v[0]; f[5] = (__bf16)v[1]; f[6] = (__bf16)v[2]; f[7] = (__bf16)v[3];
            aA[s] = f;
            *(us8*)(featb + roA + s * 32 + hi * 8) = __builtin_bit_cast(us8, f);
        }
        {
            f32x4 u = *(const f32x4*)(X + roB + s * 32 + hi * 8);
            f32x4 v = *(const f32x4*)(X + roB + s * 32 + hi * 8 + 4);
            bf16x8 f;
            f[0] = (__bf16)u[0]; f[1] = (__bf16)u[1]; f[2] = (__bf16)u[2]; f[3] = (__bf16)u[3];
            f[4] = (__bf16)v[0]; f[5] = (__bf16)v[1]; f[6] = (__bf16)v[2]; f[7] = (__bf16)v[3];
            aB[s] = f;
            if (hasB) *(us8*)(featb + roB + s * 32 + hi * 8) = __builtin_bit_cast(us8, f);
        }
    }

    // layer 1
#pragma unroll 2
    for (int t = 0; t < 4; ++t) {
        f32x4 accA = {0.f, 0.f, 0.f, 0.f}, accB = {0.f, 0.f, 0.f, 0.f};
#pragma unroll
        for (int s = 0; s < 4; ++s) {
            const bf16x8 f = ld_frg(FRG, s * 4 + t, lane);
            accA = __builtin_amdgcn_mfma_f32_16x16x32_bf16(aA[s], f, accA, 0, 0, 0);
            accB = __builtin_amdgcn_mfma_f32_16x16x32_bf16(aB[s], f, accB, 0, 0, 0);
        }
#pragma unroll
        for (int q = 0; q < 4; ++q) {
            float yA = accA[q] + b1r[t];
            yA = (yA >= 0.f) ? yA : 0.01f * yA;
            tbA[tb_off(hi * 4 + q, t * 16 + ln)] = bfbits(yA);
            float yB = accB[q] + b1r[t];
            yB = (yB >= 0.f) ? yB : 0.01f * yB;
            tbB[tb_off(hi * 4 + q, t * 16 + ln)] = bfbits(yB);
        }
    }

    // layer 2
    bf16x8 a2A[2], a2B[2];
#pragma unroll
    for (int s = 0; s < 2; ++s) {
        a2A[s] = ld_tb(tbA, ln, s * 32 + hi * 8);
        a2B[s] = ld_tb(tbB, ln, s * 32 + hi * 8);
    }
#pragma unroll 2
    for (int t = 0; t < 4; ++t) {
        f32x4 accA = {0.f, 0.f, 0.f, 0.f}, accB = {0.f, 0.f, 0.f, 0.f};
#pragma unroll
        for (int s = 0; s < 2; ++s) {
            const bf16x8 f = ld_frg(FRG, 16 + s * 4 + t, lane);
            accA = __builtin_amdgcn_mfma_f32_16x16x32_bf16(a2A[s], f, accA, 0, 0, 0);
            accB = __builtin_amdgcn_mfma_f32_16x16x32_bf16(a2B[s], f, accB, 0, 0, 0);
        }
#pragma unroll
        for (int q = 0; q < 4; ++q) {
            float yA = accA[q] + b2r[t];
            yA = (yA >= 0.f) ? yA : 0.01f * yA;
            tbA[tb_off(hi * 4 + q, t * 16 + ln)] = bfbits(yA);
            float yB = accB[q] + b2r[t];
            yB = (yB >= 0.f) ? yB : 0.01f * yB;
            tbB[tb_off(hi * 4 + q, t * 16 + ln)] = bfbits(yB);
        }
    }

    // layer 3 -> bf16 invb, staged through LDS for coalesced 16B stores
    bf16x8 a3A[2], a3B[2];
#pragma unroll
    for (int s = 0; s < 2; ++s) {
        a3A[s] = ld_tb(tbA, ln, s * 32 + hi * 8);
        a3B[s] = ld_tb(tbB, ln, s * 32 + hi * 8);
    }
#pragma unroll
    for (int half = 0; half < 2; ++half) {
#pragma unroll 2
        for (int t2 = 0; t2 < 4; ++t2) {
            const int t = half * 4 + t2;
            f32x4 accA = {0.f, 0.f, 0.f, 0.f}, accB = {0.f, 0.f, 0.f, 0.f};
#pragma unroll
            for (int s = 0; s < 2; ++s) {
                const bf16x8 f = ld_frg(FRG, 24 + s * 8 + t, lane);
                accA = __builtin_amdgcn_mfma_f32_16x16x32_bf16(a3A[s], f, accA, 0, 0, 0);
                accB = __builtin_amdgcn_mfma_f32_16x16x32_bf16(a3B[s], f, accB, 0, 0, 0);
            }
#pragma unroll
            for (int q = 0; q < 4; ++q) {
                tbA[tb_off(hi * 4 + q, t2 * 16 + ln)] = bfbits(accA[q] + b3r[t]);
                tbB[tb_off(hi * 4 + q, t2 * 16 + ln)] = bfbits(accB[q] + b3r[t]);
            }
        }
        const int rr = lane >> 2, c0 = (lane & 3) * 16;
        if (node0A + rr < N) {
            us8 w0 = __builtin_bit_cast(us8, ld_tb(tbA, rr, c0));
            us8 w1 = __builtin_bit_cast(us8, ld_tb(tbA, rr, c0 + 8));
            ushort_t* op = invb + (size_t)(node0A + rr) * H + half * 64 + c0;
            *(us8*)op = w0;
            *(us8*)(op + 8) = w1;
        }
        if (hasB && node0B + rr < N) {
            us8 w0 = __builtin_bit_cast(us8, ld_tb(tbB, rr, c0));
            us8 w1 = __builtin_bit_cast(us8, ld_tb(tbB, rr, c0 + 8));
            ushort_t* op = invb + (size_t)(node0B + rr) * H + half * 64 + c0;
            *(us8*)op = w0;
            *(us8*)(op + 8) = w1;
        }
    }
}

// ---------------- fused pass 4+5, 2 tiles per wave (unchanged, R9) -----------
__global__ __launch_bounds__(256) void mlp45_k(
    const ushort_t* __restrict__ Xb,          // neighb, bf16
    const ushort_t* __restrict__ FRGa,        // and frags
    const ushort_t* __restrict__ FRGi,        // inv frags
    const float* __restrict__ A1, const float* __restrict__ A2,
    const float* __restrict__ A3,
    const float* __restrict__ I1, const float* __restrict__ I2,
    const float* __restrict__ I3,
    float* __restrict__ OUT,
    const int* __restrict__ invp,
    int nrows, int ntiles)
{
    __shared__ __align__(16) unsigned short TB2[4 * 2 * 16 * 128];  // 32 KB
    const int tid  = threadIdx.x;
    const int wv   = tid >> 6;
    const int lane = tid & 63;
    const int ln   = lane & 15;
    const int hi   = lane >> 4;

    const int gw = blockIdx.x * 4 + wv;
    const int t0 = gw * 2;
    if (t0 >= ntiles) return;
    const bool hasB = (t0 + 1) < ntiles;
    const int node0A = t0 * 16;
    const int node0B = hasB ? (t0 + 1) * 16 : node0A;

    unsigned short* tbA = &TB2[(wv * 2) * 16 * 128];
    unsigned short* tbB = tbA + 16 * 128;

    int iqA[4], iqB[4];
#pragma unroll
    for (int q = 0; q < 4; ++q) {
        const int rA = node0A + hi * 4 + q;
        const int rB = node0B + hi * 4 + q;
        iqA[q] = (rA < nrows) ? invp[rA] : 1;
        iqB[q] = (rB < nrows) ? invp[rB] : 1;
    }

    // ---- phase A: mlp_and ----
    {
        float b1r[4], b2r[4], b3r[8];
#pragma unroll
        for (int t = 0; t < 4; ++t) b1r[t] = A1[t * 16 + ln];
#pragma unroll
        for (int t = 0; t < 4; ++t) b2r[t] = A2[t * 16 + ln];
#pragma unroll
        for (int t = 0; t < 8; ++t) b3r[t] = A3[t * 16 + ln];

        const size_t roA = (size_t)min(node0A + ln, nrows - 1) * H;
        const size_t roB = (size_t)min(node0B + ln, nrows - 1) * H;
        bf16x8 aA[4], aB[4];
#pragma unroll
        for (int s = 0; s < 4; ++s) {
            aA[s] = as_bf16x8(*(const us8*)(Xb + roA + s * 32 + hi * 8));
            aB[s] = as_bf16x8(*(const us8*)(Xb + roB + s * 32 + hi * 8));
        }

#pragma unroll 2
        for (int t = 0; t < 4; ++t) {
            f32x4 accA = {0.f, 0.f, 0.f, 0.f}, accB = {0.f, 0.f, 0.f, 0.f};
#pragma unroll
            for (int s = 0; s < 4; ++s) {
                const bf16x8 f = ld_frg(FRGa, s * 4 + t, lane);
                accA = __builtin_amdgcn_mfma_f32_16x16x32_bf16(aA[s], f, accA, 0, 0, 0);
                accB = __builtin_amdgcn_mfma_f32_16x16x32_bf16(aB[s], f, accB, 0, 0, 0);
            }
#pragma unroll
            for (int q = 0; q < 4; ++q) {
                float yA = accA[q] + b1r[t];
                yA = (yA >= 0.f) ? yA : 0.01f * yA;
                tbA[tb2_off(hi * 4 + q, t * 16 + ln)] = bfbits(yA);
                float yB = accB[q] + b1r[t];
                yB = (yB >= 0.f) ? yB : 0.01f * yB;
                tbB[tb2_off(hi * 4 + q, t * 16 + ln)] = bfbits(yB);
            }
        }

        bf16x8 a2A[2], a2B[2];
#pragma unroll
        for (int s = 0; s < 2; ++s) {
            a2A[s] = ld_tb2(tbA, ln, s * 32 + hi * 8);
            a2B[s] = ld_tb2(tbB, ln, s * 32 + hi * 8);
        }
#pragma unroll 2
        for (int t = 0; t < 4; ++t) {
            f32x4 accA = {0.f, 0.f, 0.f, 0.f}, accB = {0.f, 0.f, 0.f, 0.f};
#pragma unroll
            for (int s = 0; s < 2; ++s) {
                const bf16x8 f = ld_frg(FRGa, 16 + s * 4 + t, lane);
                accA = __builtin_amdgcn_mfma_f32_16x16x32_bf16(a2A[s], f, accA, 0, 0, 0);
                accB = __builtin_amdgcn_mfma_f32_16x16x32_bf16(a2B[s], f, accB, 0, 0, 0);
            }
#pragma unroll
            for (int q = 0; q < 4; ++q) {
                float yA = accA[q] + b2r[t];
                yA = (yA >= 0.f) ? yA : 0.01f * yA;
                tbA[tb2_off(hi * 4 + q, t * 16 + ln)] = bfbits(yA);
                float yB = accB[q] + b2r[t];
                yB = (yB >= 0.f) ? yB : 0.01f * yB;
                tbB[tb2_off(hi * 4 + q, t * 16 + ln)] = bfbits(yB);
            }
        }

        bf16x8 a3A[2], a3B[2];
#pragma unroll
        for (int s = 0; s < 2; ++s) {
            a3A[s] = ld_tb2(tbA, ln, s * 32 + hi * 8);
            a3B[s] = ld_tb2(tbB, ln, s * 32 + hi * 8);
        }
#pragma unroll 2
        for (int t = 0; t < 8; ++t) {
            f32x4 accA = {0.f, 0.f, 0.f, 0.f}, accB = {0.f, 0.f, 0.f, 0.f};
#pragma unroll
            for (int s = 0; s < 2; ++s) {
                const bf16x8 f = ld_frg(FRGa, 24 + s * 8 + t, lane);
                accA = __builtin_amdgcn_mfma_f32_16x16x32_bf16(a3A[s], f, accA, 0, 0, 0);
                accB = __builtin_amdgcn_mfma_f32_16x16x32_bf16(a3B[s], f, accB, 0, 0, 0);
            }
#pragma unroll
            for (int q = 0; q < 4; ++q) {
                const float yA = accA[q] + b3r[t];
                tbA[tb2_off(hi * 4 + q, t * 16 + ln)] = bfbits(yA);
                const int rA = node0A + hi * 4 + q;
                if (rA < nrows && !iqA[q])
                    OUT[(size_t)rA * H + t * 16 + ln] = yA;
                const float yB = accB[q] + b3r[t];
                tbB[tb2_off(hi * 4 + q, t * 16 + ln)] = bfbits(yB);
                const int rB = node0B + hi * 4 + q;
                if (hasB && rB < nrows && !iqB[q])
                    OUT[(size_t)rB * H + t * 16 + ln] = yB;
            }
        }
    }

    // ---- phase B: mlp_inv(res) for inv rows ----
    {
        float b1r[4], b2r[4], b3r[8];
#pragma unroll
        for (int t = 0; t < 4; ++t) b1r[t] = I1[t * 16 + ln];
#pragma unroll
        for (int t = 0; t < 4; ++t) b2r[t] = I2[t * 16 + ln];
#pragma unroll
        for (int t = 0; t < 8; ++t) b3r[t] = I3[t * 16 + ln];

        bf16x8 aA[4], aB[4];
#pragma unroll
        for (int s = 0; s < 4; ++s) {
            aA[s] = ld_tb2(tbA, ln, s * 32 + hi * 8);   // reads drain before writes
            aB[s] = ld_tb2(tbB, ln, s * 32 + hi * 8);
        }

#pragma unroll 2
        for (int t = 0; t < 4; ++t) {
            f32x4 accA = {0.f, 0.f, 0.f, 0.f}, accB = {0.f, 0.f, 0.f, 0.f};
#pragma unroll
            for (int s = 0; s < 4; ++s) {
                const bf16x8 f = ld_frg(FRGi, s * 4 + t, lane);
                accA = __builtin_amdgcn_mfma_f32_16x16x32_bf16(aA[s], f, accA, 0, 0, 0);
                accB = __builtin_amdgcn_mfma_f32_16x16x32_bf16(aB[s], f, accB, 0, 0, 0);
            }
#pragma unroll
            for (int q = 0; q < 4; ++q) {
                float yA = accA[q] + b1r[t];
                yA = (yA >= 0.f) ? yA : 0.01f * yA;
                tbA[tb2_off(hi * 4 + q, t * 16 + ln)] = bfbits(yA);
                float yB = accB[q] + b1r[t];
                yB = (yB >= 0.f) ? yB : 0.01f * yB;
                tbB[tb2_off(hi * 4 + q, t * 16 + ln)] = bfbits(yB);
            }
        }

        bf16x8 a2A[2], a2B[2];
#pragma unroll
        for (int s = 0; s < 2; ++s) {
            a2A[s] = ld_tb2(tbA, ln, s * 32 + hi * 8);
            a2B[s] = ld_tb2(tbB, ln, s * 32 + hi * 8);
        }
#pragma unroll 2
        for (int t = 0; t < 4; ++t) {
            f32x4 accA = {0.f, 0.f, 0.f, 0.f}, accB = {0.f, 0.f, 0.f, 0.f};
#pragma unroll
            for (int s = 0; s < 2; ++s) {
                const bf16x8 f = ld_frg(FRGi, 16 + s * 4 + t, lane);
                accA = __builtin_amdgcn_mfma_f32_16x16x32_bf16(a2A[s], f, accA, 0, 0, 0);
                accB = __builtin_amdgcn_mfma_f32_16x16x32_bf16(a2B[s], f, accB, 0, 0, 0);
            }
#pragma unroll
            for (int q = 0; q < 4; ++q) {
                float yA = accA[q] + b2r[t];
                yA = (yA >= 0.f) ? yA : 0.01f * yA;
                tbA[tb2_off(hi * 4 + q, t * 16 + ln)] = bfbits(yA);
                float yB = accB[q] + b2r[t];
                yB = (yB >= 0.f) ? yB : 0.01f * yB;
                tbB[tb2_off(hi * 4 + q, t * 16 + ln)] = bfbits(yB);
            }
        }

        bf16x8 a3A[2], a3B[2];
#pragma unroll
        for (int s = 0; s < 2; ++s) {
            a3A[s] = ld_tb2(tbA, ln, s * 32 + hi * 8);
            a3B[s] = ld_tb2(tbB, ln, s * 32 + hi * 8);
        }
#pragma unroll 2
        for (int t = 0; t < 8; ++t) {
            f32x4 accA = {0.f, 0.f, 0.f, 0.f}, accB = {0.f, 0.f, 0.f, 0.f};
#pragma unroll
            for (int s = 0; s < 2; ++s) {
                const bf16x8 f = ld_frg(FRGi, 24 + s * 8 + t, lane);
                accA = __builtin_amdgcn_mfma_f32_16x16x32_bf16(a3A[s], f, accA, 0, 0, 0);
                accB = __builtin_amdgcn_mfma_f32_16x16x32_bf16(a3B[s], f, accB, 0, 0, 0);
            }
#pragma unroll
            for (int q = 0; q < 4; ++q) {
                const int rA = node0A + hi * 4 + q;
                if (rA < nrows && iqA[q])
                    OUT[(size_t)rA * H + t * 16 + ln] = accA[q] + b3r[t];
                const int rB = node0B + hi * 4 + q;
                if (hasB && rB < nrows && iqB[q])
                    OUT[(size_t)rB * H + t * 16 + ln] = accB[q] + b3r[t];
            }
        }
    }
}

// one wave per node: 4 rows x 16 lanes x 16B, 16 rows in flight; f32 accum;
// shfl_xor(16,32) combine; bf16 mean out. deg = offsets diff.
__global__ __launch_bounds__(256) void gather_mean_k(
    const ushort_t* __restrict__ featb, const ushort_t* __restrict__ invb,
    const int* __restrict__ offsets,
    const int* __restrict__ packed, ushort_t* __restrict__ neighb, int N)
{
    const int wv = threadIdx.x >> 6, lane = threadIdx.x & 63;
    const int n = blockIdx.x * 4 + wv;
    if (n >= N) return;
    const int start = offsets[n];
    const int d = offsets[n + 1] - start;
    const int q4 = lane >> 4;                    // row-in-group 0..3
    const size_t co = (size_t)(lane & 15) * 8;   // col base
    float a[8] = {0.f, 0.f, 0.f, 0.f, 0.f, 0.f, 0.f, 0.f};
    int k = 0;
    for (; k + 15 < d; k += 16) {
        const int p0 = packed[start + k + q4];
        const int p1 = packed[start + k + 4 + q4];
        const int p2 = packed[start + k + 8 + q4];
        const int p3 = packed[start + k + 12 + q4];
        const ushort_t* t0 = (p0 < 0) ? invb : featb;
        const ushort_t* t1 = (p1 < 0) ? invb : featb;
        const ushort_t* t2 = (p2 < 0) ? invb : featb;
        const ushort_t* t3 = (p3 < 0) ? invb : featb;
        const us8 u0 = *(const us8*)(t0 + (size_t)(p0 & 0x7fffffff) * H + co);
        const us8 u1 = *(const us8*)(t1 + (size_t)(p1 & 0x7fffffff) * H + co);
        const us8 u2 = *(const us8*)(t2 + (size_t)(p2 & 0x7fffffff) * H + co);
        const us8 u3 = *(const us8*)(t3 + (size_t)(p3 & 0x7fffffff) * H + co);
#pragma unroll
        for (int i = 0; i < 8; ++i) a[i] += (bfl(u0[i]) + bfl(u1[i])) + (bfl(u2[i]) + bfl(u3[i]));
    }
    for (; k + 7 < d; k += 8) {
        const int pA = packed[start + k + q4];
        const int pB = packed[start + k + 4 + q4];
        const ushort_t* tA = (pA < 0) ? invb : featb;
        const ushort_t* tB = (pB < 0) ? invb : featb;
        const us8 uA = *(const us8*)(tA + (size_t)(pA & 0x7fffffff) * H + co);
        const us8 uB = *(const us8*)(tB + (size_t)(pB & 0x7fffffff) * H + co);
#pragma unroll
        for (int i = 0; i < 8; ++i) a[i] += bfl(uA[i]) + bfl(uB[i]);
    }
    if (k + 3 < d) {
        const int p = packed[start + k + q4];
        const ushort_t* t = (p < 0) ? invb : featb;
        const us8 u = *(const us8*)(t + (size_t)(p & 0x7fffffff) * H + co);
#pragma unroll
        for (int i = 0; i < 8; ++i) a[i] += bfl(u[i]);
        k += 4;
    }
    const int rem = d - k;
    if (q4 < rem) {
        const int p = packed[start + k + q4];
        const ushort_t* t = (p < 0) ? invb : featb;
        const us8 u = *(const us8*)(t + (size_t)(p & 0x7fffffff) * H + co);
#pragma unroll
        for (int i = 0; i < 8; ++i) a[i] += bfl(u[i]);
    }
#pragma unroll
    for (int i = 0; i < 8; ++i) {
        a[i] += __shfl_xor(a[i], 16);
        a[i] += __shfl_xor(a[i], 32);
    }
    if (q4 == 0) {
        const float scl = 1.0f / (float)max(d, 1);
        us8 o;
#pragma unroll
        for (int i = 0; i < 8; ++i) o[i] = bfbits(a[i] * scl);
        *(us8*)(neighb + (size_t)n * H + co) = o;
    }
}

extern "C" void kernel_launch(void* const* d_in, const int* in_sizes, int n_in,
                              void* d_out, int out_size, void* d_ws, size_t ws_size,
                              hipStream_t stream) {
    const float* feat = (const float*)d_in[0];
    const int*   src  = (const int*)d_in[1];
    const int*   dst  = (const int*)d_in[2];
    const int*   r    = (const int*)d_in[3];
    const int*   inv  = (const int*)d_in[4];
    const float* iw1 = (const float*)d_in[5],  *ib1 = (const float*)d_in[6];
    const float* iw2 = (const float*)d_in[7],  *ib2 = (const float*)d_in[8];
    const float* iw3 = (const float*)d_in[9],  *ib3 = (const float*)d_in[10];
    const float* aw1 = (const float*)d_in[11], *ab1 = (const float*)d_in[12];
    const float* aw2 = (const float*)d_in[13], *ab2 = (const float*)d_in[14];
    const float* aw3 = (const float*)d_in[15], *ab3 = (const float*)d_in[16];

    const int N = in_sizes[4];   // inv is [N]
    const int E = in_sizes[1];   // src is [E]

    ushort_t* featb  = (ushort_t*)d_ws;             // N*H bf16
    ushort_t* invb   = featb + (size_t)N * H;       // N*H bf16
    ushort_t* neighb = invb + (size_t)N * H;        // N*H bf16
    int* offsets = (int*)(neighb + (size_t)N * H);  // N+1
    unsigned* ebuf = (unsigned*)(offsets + (N + 1));
    int* packed  = (int*)(ebuf + E);
    ushort_t* frg = (ushort_t*)(packed + E);        // 80 frags x 512 us = 80 KB
    int* chist   = (int*)(frg + 80 * 512);
    int* cbase   = chist + 256;                     // 257
    int* ccur    = cbase + 257;

    ushort_t* frg_inv = frg;
    ushort_t* frg_and = frg + 40 * 512;

    const int ntiles = (N + 15) / 16;
    const int NB     = (N + BSZ - 1) / BSZ;         // coarse buckets (<=256)
    const int cgrid  = (E + ACH - 1) / ACH;
    const int gp1    = (ntiles + 7) / 8;            // pass1: 4 waves x 2 tiles
    const int g45    = (ntiles + 7) / 8;            // mlp45: 4 waves x 2 tiles

    hipMemsetAsync(chist, 0, 256 * sizeof(int), stream);

    // 1) coarse histogram || weight frag pre-pack
    prep_hist_k<<<cgrid + 20, 256, 0, stream>>>(dst, chist, iw1, iw2, iw3,
                                                aw1, aw2, aw3, frg, E, cgrid);
    // 2) coarse-bucket scan
    cscan_k<<<1, 256, 0, stream>>>(chist, cbase, ccur, NB, E);
    // 3) coarse bin pass
    coarse_bin_k<<<cgrid, 256, 0, stream>>>(src, dst, r, ccur, ebuf, E);
    // 4) fine CSR build || pass1 (invb = bf16(mlp_inv(feat)), featb = bf16(feat))
    pass1_fine_k<<<NB + gp1, 256, 0, stream>>>(feat, frg_inv, ib1, ib2, ib3,
                                               invb, featb, ebuf, cbase,
                                               offsets, packed, N, E, NB, ntiles);
    // 5) neighb = bf16(mean of messages by dst)
    gather_mean_k<<<(N + 3) / 4, 256, 0, stream>>>(featb, invb, offsets,
                                                   packed, neighb, N);
    // 6) fused: res = mlp_and(neighb); out = inv ? mlp_inv(res) : res
    mlp45_k<<<g45, 256, 0, stream>>>(neighb, frg_and, frg_inv,
                                     ab1, ab2, ab3, ib1, ib2, ib3,
                                     (float*)d_out, inv, N, ntiles);
}

// Round 12
// 133.794 us; speedup vs baseline: 3.3246x; 1.0709x over previous
//
#include <hip/hip_runtime.h>

// FuncConv: out = select(inv, mlp_inv(res), res); res = mlp_and(mean_dst(msg));
// msg = select(r, mlp_inv(feat[src]), feat[src]).
// R11: (a) gather_mean was latency-bound (2.4 TB/s vs 6.3 ceiling, 1 dep chain
//     per wave): now 2 nodes/wave (independent chains, lanes split 32/32) with
//     8-deep edge unroll (4 row loads in flight per lane).
// (b) ACH 2048->4096: coarse bucket runs 21 entries (84B) -> better ebuf
//     write coalescing, half the reservation atomics.
//
// ws: featb[N*H bf16] invb[N*H bf16] neighb[N*H bf16]
//     offsets[N+1] ebuf[E] packed[E] frg[80*512 us] chist[256] cbase[257] ccur[256]

#define H 128
#define HH 64
#define BSH 9     // log2 nodes per coarse bucket
#define BSZ 512   // nodes per coarse bucket
#define ACH 4096  // edges per coarse block

typedef float f32x4 __attribute__((ext_vector_type(4)));
typedef __bf16 bf16x8 __attribute__((ext_vector_type(8)));
typedef unsigned short us8 __attribute__((ext_vector_type(8)));
typedef unsigned short ushort_t;

__device__ __forceinline__ unsigned short bfbits(float f) {
    __bf16 h = (__bf16)f;                       // RNE convert
    return __builtin_bit_cast(unsigned short, h);
}
__device__ __forceinline__ bf16x8 as_bf16x8(us8 v) {
    return __builtin_bit_cast(bf16x8, v);
}
__device__ __forceinline__ float bfl(unsigned short u) {
    return __builtin_bit_cast(float, ((unsigned)u) << 16);
}

// per-wave transpose buffers, XOR-swizzled (byte ^= (row&7)<<4; 16B groups)
__device__ __forceinline__ int tb_off(int m, int j) {      // 16 x 64 bf16
    return m * 64 + ((((j * 2) ^ ((m & 7) << 4))) >> 1);
}
__device__ __forceinline__ int tb2_off(int m, int j) {     // 16 x 128 bf16
    return m * 128 + ((((j * 2) ^ ((m & 7) << 4))) >> 1);
}
__device__ __forceinline__ bf16x8 ld_tb(const unsigned short* tb, int m, int j0) {
    return as_bf16x8(*(const us8*)&tb[tb_off(m, j0)]);
}
__device__ __forceinline__ bf16x8 ld_tb2(const unsigned short* tb, int m, int j0) {
    return as_bf16x8(*(const us8*)&tb[tb2_off(m, j0)]);
}
// weight B-fragment from global (L1/L2-hot, 40KB working set per MLP)
__device__ __forceinline__ bf16x8 ld_frg(const ushort_t* __restrict__ FRG, int fid, int lane) {
    return as_bf16x8(*(const us8*)&FRG[(fid * 64 + lane) * 8]);
}

// ---------------- fused: coarse dst-histogram || weight frag pre-pack --------
__global__ __launch_bounds__(256) void prep_hist_k(
    const int* __restrict__ dst, int* __restrict__ chist,
    const float* __restrict__ iw1, const float* __restrict__ iw2,
    const float* __restrict__ iw3,
    const float* __restrict__ aw1, const float* __restrict__ aw2,
    const float* __restrict__ aw3,
    ushort_t* __restrict__ frg, int E, int cgrid)
{
    __shared__ int h[256];
    const int tid = threadIdx.x;
    if (blockIdx.x < cgrid) {
        h[tid] = 0;
        __syncthreads();
        const int base = blockIdx.x * ACH;
#pragma unroll
        for (int j = 0; j < 16; ++j) {
            const int e = base + j * 256 + tid;
            if (e < E) atomicAdd(&h[dst[e] >> BSH], 1);
        }
        __syncthreads();
        if (h[tid]) atomicAdd(&chist[tid], h[tid]);
    } else {
        const int g = (blockIdx.x - cgrid) * 256 + tid;     // 80*64 = 5120
        const int fid2 = g >> 6;
        if (fid2 >= 80) return;
        const int lane = g & 63;
        const int ln = lane & 15, hi = lane >> 4;
        const int set = fid2 / 40;
        const int fid = fid2 - set * 40;
        const float* w; int inF, s, t;
        if (fid < 16)      { w = set ? aw1 : iw1; inF = H;  s = fid >> 2;        t = fid & 3; }
        else if (fid < 24) { w = set ? aw2 : iw2; inF = HH; s = (fid - 16) >> 2; t = (fid - 16) & 3; }
        else               { w = set ? aw3 : iw3; inF = HH; s = (fid - 24) >> 3; t = (fid - 24) & 7; }
        const float* p = w + (size_t)(t * 16 + ln) * inF + (s * 32 + hi * 8);
        f32x4 a = *(const f32x4*)p;
        f32x4 b = *(const f32x4*)(p + 4);
        ushort_t* d = &frg[(size_t)(fid2 * 64 + lane) * 8];
        d[0] = bfbits(a[0]); d[1] = bfbits(a[1]); d[2] = bfbits(a[2]); d[3] = bfbits(a[3]);
        d[4] = bfbits(b[0]); d[5] = bfbits(b[1]); d[6] = bfbits(b[2]); d[7] = bfbits(b[3]);
    }
}

// single block: coarse-bucket exclusive scan -> cbase/ccur
__global__ __launch_bounds__(256) void cscan_k(
    const int* __restrict__ chist, int* __restrict__ cbase, int* __restrict__ ccur,
    int nb, int E)
{
    __shared__ int s[256];
    const int tid = threadIdx.x;
    const int v = (tid < nb) ? chist[tid] : 0;
    s[tid] = v;
    __syncthreads();
    for (int st = 1; st < 256; st <<= 1) {
        int t = (tid >= st) ? s[tid - st] : 0;
        __syncthreads();
        s[tid] += t;
        __syncthreads();
    }
    const int excl = s[tid] - v;
    if (tid < nb) { cbase[tid] = excl; ccur[tid] = excl; }
    if (tid == 0) cbase[nb] = E;
}

// coarse pass: bin edges by dst>>BSH; entry = (dloc<<18)|(src<<1)|r
__global__ __launch_bounds__(256) void coarse_bin_k(
    const int* __restrict__ src, const int* __restrict__ dst,
    const int* __restrict__ r,
    int* __restrict__ ccur, unsigned* __restrict__ ebuf, int E)
{
    __shared__ int hcnt[256];
    __shared__ int gbase[256];
    __shared__ int lcur[256];
    const int tid = threadIdx.x;
    hcnt[tid] = 0;
    __syncthreads();
    const int base = blockIdx.x * ACH;
    unsigned v[16]; int bk[16];
#pragma unroll
    for (int j = 0; j < 16; ++j) {
        const int e = base + j * 256 + tid;
        if (e < E) {
            const int d = dst[e];
            bk[j] = d >> BSH;
            v[j] = ((unsigned)(d & (BSZ - 1)) << 18) |
                   ((unsigned)src[e] << 1) | (unsigned)r[e];
            atomicAdd(&hcnt[bk[j]], 1);
        } else bk[j] = -1;
    }
    __syncthreads();
    const int c = hcnt[tid];
    gbase[tid] = (c > 0) ? atomicAdd(&ccur[tid], c) : 0;
    lcur[tid] = 0;
    __syncthreads();
#pragma unroll
    for (int j = 0; j < 16; ++j) {
        if (bk[j] >= 0) {
            const int loc = atomicAdd(&lcur[bk[j]], 1);
            ebuf[gbase[bk[j]] + loc] = v[j];
        }
    }
}

// ---------------- fused: fine_build || MLP pass 1 -----------------------------
// 256 threads. blocks [0,NB): per 512-node bucket CSR build (pair-per-thread
// scan). blocks [NB,..): pass1 MLP, 4 waves x 2 tiles, shared frag loads.
__global__ __launch_bounds__(256) void pass1_fine_k(
    const float* __restrict__ X,
    const ushort_t* __restrict__ FRG,
    const float* __restrict__ B1, const float* __restrict__ B2,
    const float* __restrict__ B3,
    ushort_t* __restrict__ invb, ushort_t* __restrict__ featb,
    const unsigned* __restrict__ ebuf, const int* __restrict__ cbase,
    int* __restrict__ offsets, int* __restrict__ packed,
    int N, int E, int NB, int ntiles)
{
    __shared__ __align__(16) unsigned short TBs[4 * 2 * 16 * 64];  // 16 KB
    const int tid = threadIdx.x;

    if (blockIdx.x < NB) {
        // ------- fine_build body, 256 threads over 512 bucket slots ----------
        int* lcur = (int*)TBs;            // 512 ints
        int* ps   = lcur + BSZ;           // 256 ints
        const int b = blockIdx.x;
        const int lo = b << BSH;
        const int nn = min(BSZ, N - lo);
        const int rstart = cbase[b];
        const int rend   = cbase[b + 1];
        lcur[tid] = 0; lcur[tid + 256] = 0;
        __syncthreads();
        for (int i = rstart + tid; i < rend; i += 256)
            atomicAdd(&lcur[ebuf[i] >> 18], 1);
        __syncthreads();
        const int v0 = lcur[2 * tid];
        const int v1 = lcur[2 * tid + 1];
        const int psum = v0 + v1;
        ps[tid] = psum;
        __syncthreads();
        for (int st = 1; st < 256; st <<= 1) {
            int t = (tid >= st) ? ps[tid - st] : 0;
            __syncthreads();
            ps[tid] += t;
            __syncthreads();
        }
        const int e0 = rstart + ps[tid] - psum;     // exclusive prefix
        const int e1 = e0 + v0;
        if (2 * tid < nn)     offsets[lo + 2 * tid] = e0;
        if (2 * tid + 1 < nn) offsets[lo + 2 * tid + 1] = e1;
        if (b == NB - 1 && tid == 0) offsets[N] = E;
        __syncthreads();
        lcur[2 * tid] = e0;
        lcur[2 * tid + 1] = e1;
        __syncthreads();
        for (int i = rstart + tid; i < rend; i += 256) {
            const unsigned w = ebuf[i];
            const int dloc = w >> 18;
            const int pos = atomicAdd(&lcur[dloc], 1);
            packed[pos] = (int)(((w & 0x3ffffu) >> 1) | ((w & 1u) << 31));
        }
        return;
    }

    // ------- MLP pass-1 body: 4 waves x 2 tiles, shared frag loads -----------
    const int wv   = tid >> 6;
    const int lane = tid & 63;
    const int ln   = lane & 15;
    const int hi   = lane >> 4;

    const int gw = (blockIdx.x - NB) * 4 + wv;
    const int t0 = gw * 2;
    if (t0 >= ntiles) return;
    const bool hasB = (t0 + 1) < ntiles;
    const int node0A = t0 * 16;
    const int node0B = hasB ? (t0 + 1) * 16 : node0A;

    float b1r[4], b2r[4], b3r[8];
#pragma unroll
    for (int t = 0; t < 4; ++t) b1r[t] = B1[t * 16 + ln];
#pragma unroll
    for (int t = 0; t < 4; ++t) b2r[t] = B2[t * 16 + ln];
#pragma unroll
    for (int t = 0; t < 8; ++t) b3r[t] = B3[t * 16 + ln];

    unsigned short* tbA = &TBs[(wv * 2) * 16 * 64];
    unsigned short* tbB = tbA + 16 * 64;

    const size_t roA = (size_t)min(node0A + ln, N - 1) * H;
    const size_t roB = (size_t)min(node0B + ln, N - 1) * H;

    bf16x8 aA[4], aB[4];
#pragma unroll
    for (int s = 0; s < 4; ++s) {
        {
            f32x4 u = *(const f32x4*)(X + roA + s * 32 + hi * 8);
            f32x4 v = *(const f32x4*)(X + roA + s * 32 + hi * 8 + 4);
            bf16x8 f;
            f[0] = (__bf16)u[0]; f[1] = (__bf16)u[1]; f[2] = (__bf16)u[2]; f[3] = (__bf16)u[3];
            f[4] = (__bf16)v[0]; f[5] = (__bf16)v[1]; f[6] = (__bf16)v[2]; f[7] = (__bf16)v[3];
            aA[s] = f;
            *(us8*)(featb + roA + s * 32 + hi * 8) = __builtin_bit_cast(us8, f);
        }
        {
            f32x4 u = *(const f32x4*)(X + roB + s * 32 + hi * 8);
            f32x4 v = *(const f32x4*)(X + roB + s * 32 + hi * 8 + 4);
            bf16x8 f;
            f[0] = (__bf16)u[0]; f[1] = (__bf16)u[1]; f[2] = (__bf16)u[2]; f[3] = (__bf16)u[3];
            f[4] = (__bf16)v[0]; f[5] = (__bf16)v[1]; f[6] = (__bf16)v[2]; f[7] = (__bf16)v[3];
            aB[s] = f;
            if (hasB) *(us8*)(featb + roB + s * 32 + hi * 8) = __builtin_bit_cast(us8, f);
        }
    }

    // layer 1
#pragma unroll 2
    for (int t = 0; t < 4; ++t) {
        f32x4 accA = {0.f, 0.f, 0.f, 0.f}, accB = {0.f, 0.f, 0.f, 0.f};
#pragma unroll
        for (int s = 0; s < 4; ++s) {
            const bf16x8 f = ld_frg(FRG, s * 4 + t, lane);
            accA = __builtin_amdgcn_mfma_f32_16x16x32_bf16(aA[s], f, accA, 0, 0, 0);
            accB = __builtin_amdgcn_mfma_f32_16x16x32_bf16(aB[s], f, accB, 0, 0, 0);
        }
#pragma unroll
        for (int q = 0; q < 4; ++q) {
            float yA = accA[q] + b1r[t];
            yA = (yA >= 0.f) ? yA : 0.01f * yA;
            tbA[tb_off(hi * 4 + q, t * 16 + ln)] = bfbits(yA);
            float yB = accB[q] + b1r[t];
            yB = (yB >= 0.f) ? yB : 0.01f * yB;
            tbB[tb_off(hi * 4 + q, t * 16 + ln)] = bfbits(yB);
        }
    }

    // layer 2
    bf16x8 a2A[2], a2B[2];
#pragma unroll
    for (int s = 0; s < 2; ++s) {
        a2A[s] = ld_tb(tbA, ln, s * 32 + hi * 8);
        a2B[s] = ld_tb(tbB, ln, s * 32 + hi * 8);
    }
#pragma unroll 2
    for (int t = 0; t < 4; ++t) {
        f32x4 accA = {0.f, 0.f, 0.f, 0.f}, accB = {0.f, 0.f, 0.f, 0.f};
#pragma unroll
        for (int s = 0; s < 2; ++s) {
            const bf16x8 f = ld_frg(FRG, 16 + s * 4 + t, lane);
            accA = __builtin_amdgcn_mfma_f32_16x16x32_bf16(a2A[s], f, accA, 0, 0, 0);
            accB = __builtin_amdgcn_mfma_f32_16x16x32_bf16(a2B[s], f, accB, 0, 0, 0);
        }
#pragma unroll
        for (int q = 0; q < 4; ++q) {
            float yA = accA[q] + b2r[t];
            yA = (yA >= 0.f) ? yA : 0.01f * yA;
            tbA[tb_off(hi * 4 + q, t * 16 + ln)] = bfbits(yA);
            float yB = accB[q] + b2r[t];
            yB = (yB >= 0.f) ? yB : 0.01f * yB;
            tbB[tb_off(hi * 4 + q, t * 16 + ln)] = bfbits(yB);
        }
    }

    // layer 3 -> bf16 invb, staged through LDS for coalesced 16B stores
    bf16x8 a3A[2], a3B[2];
#pragma unroll
    for (int s = 0; s < 2; ++s) {
        a3A[s] = ld_tb(tbA, ln, s * 32 + hi * 8);
        a3B[s] = ld_tb(tbB, ln, s * 32 + hi * 8);
    }
#pragma unroll
    for (int half = 0; half < 2; ++half) {
#pragma unroll 2
        for (int t2 = 0; t2 < 4; ++t2) {
            const int t = half * 4 + t2;
            f32x4 accA = {0.f, 0.f, 0.f, 0.f}, accB = {0.f, 0.f, 0.f, 0.f};
#pragma unroll
            for (int s = 0; s < 2; ++s) {
                const bf16x8 f = ld_frg(FRG, 24 + s * 8 + t, lane);
                accA = __builtin_amdgcn_mfma_f32_16x16x32_bf16(a3A[s], f, accA, 0, 0, 0);
                accB = __builtin_amdgcn_mfma_f32_16x16x32_bf16(a3B[s], f, accB, 0, 0, 0);
            }
#pragma unroll
            for (int q = 0; q < 4; ++q) {
                tbA[tb_off(hi * 4 + q, t2 * 16 + ln)] = bfbits(accA[q] + b3r[t]);
                tbB[tb_off(hi * 4 + q, t2 * 16 + ln)] = bfbits(accB[q] + b3r[t]);
            }
        }
        const int rr = lane >> 2, c0 = (lane & 3) * 16;
        if (node0A + rr < N) {
            us8 w0 = __builtin_bit_cast(us8, ld_tb(tbA, rr, c0));
            us8 w1 = __builtin_bit_cast(us8, ld_tb(tbA, rr, c0 + 8));
            ushort_t* op = invb + (size_t)(node0A + rr) * H + half * 64 + c0;
            *(us8*)op = w0;
            *(us8*)(op + 8) = w1;
        }
        if (hasB && node0B + rr < N) {
            us8 w0 = __builtin_bit_cast(us8, ld_tb(tbB, rr, c0));
            us8 w1 = __builtin_bit_cast(us8, ld_tb(tbB, rr, c0 + 8));
            ushort_t* op = invb + (size_t)(node0B + rr) * H + half * 64 + c0;
            *(us8*)op = w0;
            *(us8*)(op + 8) = w1;
        }
    }
}

// ---------------- fused pass 4+5, 2 tiles per wave (unchanged, R9/R10) -------
__global__ __launch_bounds__(256) void mlp45_k(
    const ushort_t* __restrict__ Xb,          // neighb, bf16
    const ushort_t* __restrict__ FRGa,        // and frags
    const ushort_t* __restrict__ FRGi,        // inv frags
    const float* __restrict__ A1, const float* __restrict__ A2,
    const float* __restrict__ A3,
    const float* __restrict__ I1, const float* __restrict__ I2,
    const float* __restrict__ I3,
    float* __restrict__ OUT,
    const int* __restrict__ invp,
    int nrows, int ntiles)
{
    __shared__ __align__(16) unsigned short TB2[4 * 2 * 16 * 128];  // 32 KB
    const int tid  = threadIdx.x;
    const int wv   = tid >> 6;
    const int lane = tid & 63;
    const int ln   = lane & 15;
    const int hi   = lane >> 4;

    const int gw = blockIdx.x * 4 + wv;
    const int t0 = gw * 2;
    if (t0 >= ntiles) return;
    const bool hasB = (t0 + 1) < ntiles;
    const int node0A = t0 * 16;
    const int node0B = hasB ? (t0 + 1) * 16 : node0A;

    unsigned short* tbA = &TB2[(wv * 2) * 16 * 128];
    unsigned short* tbB = tbA + 16 * 128;

    int iqA[4], iqB[4];
#pragma unroll
    for (int q = 0; q < 4; ++q) {
        const int rA = node0A + hi * 4 + q;
        const int rB = node0B + hi * 4 + q;
        iqA[q] = (rA < nrows) ? invp[rA] : 1;
        iqB[q] = (rB < nrows) ? invp[rB] : 1;
    }

    // ---- phase A: mlp_and ----
    {
        float b1r[4], b2r[4], b3r[8];
#pragma unroll
        for (int t = 0; t < 4; ++t) b1r[t] = A1[t * 16 + ln];
#pragma unroll
        for (int t = 0; t < 4; ++t) b2r[t] = A2[t * 16 + ln];
#pragma unroll
        for (int t = 0; t < 8; ++t) b3r[t] = A3[t * 16 + ln];

        const size_t roA = (size_t)min(node0A + ln, nrows - 1) * H;
        const size_t roB = (size_t)min(node0B + ln, nrows - 1) * H;
        bf16x8 aA[4], aB[4];
#pragma unroll
        for (int s = 0; s < 4; ++s) {
            aA[s] = as_bf16x8(*(const us8*)(Xb + roA + s * 32 + hi * 8));
            aB[s] = as_bf16x8(*(const us8*)(Xb + roB + s * 32 + hi * 8));
        }

#pragma unroll 2
        for (int t = 0; t < 4; ++t) {
            f32x4 accA = {0.f, 0.f, 0.f, 0.f}, accB = {0.f, 0.f, 0.f, 0.f};
#pragma unroll
            for (int s = 0; s < 4; ++s) {
                const bf16x8 f = ld_frg(FRGa, s * 4 + t, lane);
                accA = __builtin_amdgcn_mfma_f32_16x16x32_bf16(aA[s], f, accA, 0, 0, 0);
                accB = __builtin_amdgcn_mfma_f32_16x16x32_bf16(aB[s], f, accB, 0, 0, 0);
            }
#pragma unroll
            for (int q = 0; q < 4; ++q) {
                float yA = accA[q] + b1r[t];
                yA = (yA >= 0.f) ? yA : 0.01f * yA;
                tbA[tb2_off(hi * 4 + q, t * 16 + ln)] = bfbits(yA);
                float yB = accB[q] + b1r[t];
                yB = (yB >= 0.f) ? yB : 0.01f * yB;
                tbB[tb2_off(hi * 4 + q, t * 16 + ln)] = bfbits(yB);
            }
        }

        bf16x8 a2A[2], a2B[2];
#pragma unroll
        for (int s = 0; s < 2; ++s) {
            a2A[s] = ld_tb2(tbA, ln, s * 32 + hi * 8);
            a2B[s] = ld_tb2(tbB, ln, s * 32 + hi * 8);
        }
#pragma unroll 2
        for (int t = 0; t < 4; ++t) {
            f32x4 accA = {0.f, 0.f, 0.f, 0.f}, accB = {0.f, 0.f, 0.f, 0.f};
#pragma unroll
            for (int s = 0; s < 2; ++s) {
                const bf16x8 f = ld_frg(FRGa, 16 + s * 4 + t, lane);
                accA = __builtin_amdgcn_mfma_f32_16x16x32_bf16(a2A[s], f, accA, 0, 0, 0);
                accB = __builtin_amdgcn_mfma_f32_16x16x32_bf16(a2B[s], f, accB, 0, 0, 0);
            }
#pragma unroll
            for (int q = 0; q < 4; ++q) {
                float yA = accA[q] + b2r[t];
                yA = (yA >= 0.f) ? yA : 0.01f * yA;
                tbA[tb2_off(hi * 4 + q, t * 16 + ln)] = bfbits(yA);
                float yB = accB[q] + b2r[t];
                yB = (yB >= 0.f) ? yB : 0.01f * yB;
                tbB[tb2_off(hi * 4 + q, t * 16 + ln)] = bfbits(yB);
            }
        }

        bf16x8 a3A[2], a3B[2];
#pragma unroll
        for (int s = 0; s < 2; ++s) {
            a3A[s] = ld_tb2(tbA, ln, s * 32 + hi * 8);
            a3B[s] = ld_tb2(tbB, ln, s * 32 + hi * 8);
        }
#pragma unroll 2
        for (int t = 0; t < 8; ++t) {
            f32x4 accA = {0.f, 0.f, 0.f, 0.f}, accB = {0.f, 0.f, 0.f, 0.f};
#pragma unroll
            for (int s = 0; s < 2; ++s) {
                const bf16x8 f = ld_frg(FRGa, 24 + s * 8 + t, lane);
                accA = __builtin_amdgcn_mfma_f32_16x16x32_bf16(a3A[s], f, accA, 0, 0, 0);
                accB = __builtin_amdgcn_mfma_f32_16x16x32_bf16(a3B[s], f, accB, 0, 0, 0);
            }
#pragma unroll
            for (int q = 0; q < 4; ++q) {
                const float yA = accA[q] + b3r[t];
                tbA[tb2_off(hi * 4 + q, t * 16 + ln)] = bfbits(yA);
                const int rA = node0A + hi * 4 + q;
                if (rA < nrows && !iqA[q])
                    OUT[(size_t)rA * H + t * 16 + ln] = yA;
                const float yB = accB[q] + b3r[t];
                tbB[tb2_off(hi * 4 + q, t * 16 + ln)] = bfbits(yB);
                const int rB = node0B + hi * 4 + q;
                if (hasB && rB < nrows && !iqB[q])
                    OUT[(size_t)rB * H + t * 16 + ln] = yB;
            }
        }
    }

    // ---- phase B: mlp_inv(res) for inv rows ----
    {
        float b1r[4], b2r[4], b3r[8];
#pragma unroll
        for (int t = 0; t < 4; ++t) b1r[t] = I1[t * 16 + ln];
#pragma unroll
        for (int t = 0; t < 4; ++t) b2r[t] = I2[t * 16 + ln];
#pragma unroll
        for (int t = 0; t < 8; ++t) b3r[t] = I3[t * 16 + ln];

        bf16x8 aA[4], aB[4];
#pragma unroll
        for (int s = 0; s < 4; ++s) {
            aA[s] = ld_tb2(tbA, ln, s * 32 + hi * 8);   // reads drain before writes
            aB[s] = ld_tb2(tbB, ln, s * 32 + hi * 8);
        }

#pragma unroll 2
        for (int t = 0; t < 4; ++t) {
            f32x4 accA = {0.f, 0.f, 0.f, 0.f}, accB = {0.f, 0.f, 0.f, 0.f};
#pragma unroll
            for (int s = 0; s < 4; ++s) {
                const bf16x8 f = ld_frg(FRGi, s * 4 + t, lane);
                accA = __builtin_amdgcn_mfma_f32_16x16x32_bf16(aA[s], f, accA, 0, 0, 0);
                accB = __builtin_amdgcn_mfma_f32_16x16x32_bf16(aB[s], f, accB, 0, 0, 0);
            }
#pragma unroll
            for (int q = 0; q < 4; ++q) {
                float yA = accA[q] + b1r[t];
                yA = (yA >= 0.f) ? yA : 0.01f * yA;
                tbA[tb2_off(hi * 4 + q, t * 16 + ln)] = bfbits(yA);
                float yB = accB[q] + b1r[t];
                yB = (yB >= 0.f) ? yB : 0.01f * yB;
                tbB[tb2_off(hi * 4 + q, t * 16 + ln)] = bfbits(yB);
            }
        }

        bf16x8 a2A[2], a2B[2];
#pragma unroll
        for (int s = 0; s < 2; ++s) {
            a2A[s] = ld_tb2(tbA, ln, s * 32 + hi * 8);
            a2B[s] = ld_tb2(tbB, ln, s * 32 + hi * 8);
        }
#pragma unroll 2
        for (int t = 0; t < 4; ++t) {
            f32x4 accA = {0.f, 0.f, 0.f, 0.f}, accB = {0.f, 0.f, 0.f, 0.f};
#pragma unroll
            for (int s = 0; s < 2; ++s) {
                const bf16x8 f = ld_frg(FRGi, 16 + s * 4 + t, lane);
                accA = __builtin_amdgcn_mfma_f32_16x16x32_bf16(a2A[s], f, accA, 0, 0, 0);
                accB = __builtin_amdgcn_mfma_f32_16x16x32_bf16(a2B[s], f, accB, 0, 0, 0);
            }
#pragma unroll
            for (int q = 0; q < 4; ++q) {
                float yA = accA[q] + b2r[t];
                yA = (yA >= 0.f) ? yA : 0.01f * yA;
                tbA[tb2_off(hi * 4 + q, t * 16 + ln)] = bfbits(yA);
                float yB = accB[q] + b2r[t];
                yB = (yB >= 0.f) ? yB : 0.01f * yB;
                tbB[tb2_off(hi * 4 + q, t * 16 + ln)] = bfbits(yB);
            }
        }

        bf16x8 a3A[2], a3B[2];
#pragma unroll
        for (int s = 0; s < 2; ++s) {
            a3A[s] = ld_tb2(tbA, ln, s * 32 + hi * 8);
            a3B[s] = ld_tb2(tbB, ln, s * 32 + hi * 8);
        }
#pragma unroll 2
        for (int t = 0; t < 8; ++t) {
            f32x4 accA = {0.f, 0.f, 0.f, 0.f}, accB = {0.f, 0.f, 0.f, 0.f};
#pragma unroll
            for (int s = 0; s < 2; ++s) {
                const bf16x8 f = ld_frg(FRGi, 24 + s * 8 + t, lane);
                accA = __builtin_amdgcn_mfma_f32_16x16x32_bf16(a3A[s], f, accA, 0, 0, 0);
                accB = __builtin_amdgcn_mfma_f32_16x16x32_bf16(a3B[s], f, accB, 0, 0, 0);
            }
#pragma unroll
            for (int q = 0; q < 4; ++q) {
                const int rA = node0A + hi * 4 + q;
                if (rA < nrows && iqA[q])
                    OUT[(size_t)rA * H + t * 16 + ln] = accA[q] + b3r[t];
                const int rB = node0B + hi * 4 + q;
                if (hasB && rB < nrows && iqB[q])
                    OUT[(size_t)rB * H + t * 16 + ln] = accB[q] + b3r[t];
            }
        }
    }
}

// 2 nodes per wave (lanes split 32/32 -> 2 independent chains); per node:
// 2 row-groups x 16 lanes x us8, 8-deep edge unroll (4 row loads in flight
// per lane). f32 accum; shfl_xor(16) combine; bf16 mean out.
__global__ __launch_bounds__(256) void gather_mean_k(
    const ushort_t* __restrict__ featb, const ushort_t* __restrict__ invb,
    const int* __restrict__ offsets,
    const int* __restrict__ packed, ushort_t* __restrict__ neighb, int N)
{
    const int wv = threadIdx.x >> 6, lane = threadIdx.x & 63;
    const int pair = blockIdx.x * 4 + wv;
    const int n0 = pair * 2;
    if (n0 >= N) return;
    const int half = lane >> 5;                   // node select within wave
    const int nid = n0 + half;
    const bool act = nid < N;
    const int n = min(nid, N - 1);
    const int start = offsets[n];
    const int d = offsets[n + 1] - start;
    const int q2 = (lane >> 4) & 1;               // row-in-group 0/1
    const size_t co = (size_t)(lane & 15) * 8;    // col base (8 bf16 = 16B)
    float a[8] = {0.f, 0.f, 0.f, 0.f, 0.f, 0.f, 0.f, 0.f};
    int k = 0;
    for (; k + 7 < d; k += 8) {
        const int p0 = packed[start + k + q2];
        const int p1 = packed[start + k + 2 + q2];
        const int p2 = packed[start + k + 4 + q2];
        const int p3 = packed[start + k + 6 + q2];
        const ushort_t* t0 = (p0 < 0) ? invb : featb;
        const ushort_t* t1 = (p1 < 0) ? invb : featb;
        const ushort_t* t2 = (p2 < 0) ? invb : featb;
        const ushort_t* t3 = (p3 < 0) ? invb : featb;
        const us8 u0 = *(const us8*)(t0 + (size_t)(p0 & 0x7fffffff) * H + co);
        const us8 u1 = *(const us8*)(t1 + (size_t)(p1 & 0x7fffffff) * H + co);
        const us8 u2 = *(const us8*)(t2 + (size_t)(p2 & 0x7fffffff) * H + co);
        const us8 u3 = *(const us8*)(t3 + (size_t)(p3 & 0x7fffffff) * H + co);
#pragma unroll
        for (int i = 0; i < 8; ++i) a[i] += (bfl(u0[i]) + bfl(u1[i])) + (bfl(u2[i]) + bfl(u3[i]));
    }
    if (k + 3 < d) {
        const int pA = packed[start + k + q2];
        const int pB = packed[start + k + 2 + q2];
        const ushort_t* tA = (pA < 0) ? invb : featb;
        const ushort_t* tB = (pB < 0) ? invb : featb;
        const us8 uA = *(const us8*)(tA + (size_t)(pA & 0x7fffffff) * H + co);
        const us8 uB = *(const us8*)(tB + (size_t)(pB & 0x7fffffff) * H + co);
#pragma unroll
        for (int i = 0; i < 8; ++i) a[i] += bfl(uA[i]) + bfl(uB[i]);
        k += 4;
    }
    if (k + q2 < d) {
        const int p = packed[start + k + q2];
        const ushort_t* t = (p < 0) ? invb : featb;
        const us8 u = *(const us8*)(t + (size_t)(p & 0x7fffffff) * H + co);
#pragma unroll
        for (int i = 0; i < 8; ++i) a[i] += bfl(u[i]);
    }
    if (k + 2 + q2 < d) {
        const int p = packed[start + k + 2 + q2];
        const ushort_t* t = (p < 0) ? invb : featb;
        const us8 u = *(const us8*)(t + (size_t)(p & 0x7fffffff) * H + co);
#pragma unroll
        for (int i = 0; i < 8; ++i) a[i] += bfl(u[i]);
    }
#pragma unroll
    for (int i = 0; i < 8; ++i)
        a[i] += __shfl_xor(a[i], 16);     // combine q2 pair (stays within half)
    if (q2 == 0 && act) {
        const float scl = 1.0f / (float)max(d, 1);
        us8 o;
#pragma unroll
        for (int i = 0; i < 8; ++i) o[i] = bfbits(a[i] * scl);
        *(us8*)(neighb + (size_t)n * H + co) = o;
    }
}

extern "C" void kernel_launch(void* const* d_in, const int* in_sizes, int n_in,
                              void* d_out, int out_size, void* d_ws, size_t ws_size,
                              hipStream_t stream) {
    const float* feat = (const float*)d_in[0];
    const int*   src  = (const int*)d_in[1];
    const int*   dst  = (const int*)d_in[2];
    const int*   r    = (const int*)d_in[3];
    const int*   inv  = (const int*)d_in[4];
    const float* iw1 = (const float*)d_in[5],  *ib1 = (const float*)d_in[6];
    const float* iw2 = (const float*)d_in[7],  *ib2 = (const float*)d_in[8];
    const float* iw3 = (const float*)d_in[9],  *ib3 = (const float*)d_in[10];
    const float* aw1 = (const float*)d_in[11], *ab1 = (const float*)d_in[12];
    const float* aw2 = (const float*)d_in[13], *ab2 = (const float*)d_in[14];
    const float* aw3 = (const float*)d_in[15], *ab3 = (const float*)d_in[16];

    const int N = in_sizes[4];   // inv is [N]
    const int E = in_sizes[1];   // src is [E]

    ushort_t* featb  = (ushort_t*)d_ws;             // N*H bf16
    ushort_t* invb   = featb + (size_t)N * H;       // N*H bf16
    ushort_t* neighb = invb + (size_t)N * H;        // N*H bf16
    int* offsets = (int*)(neighb + (size_t)N * H);  // N+1
    unsigned* ebuf = (unsigned*)(offsets + (N + 1));
    int* packed  = (int*)(ebuf + E);
    ushort_t* frg = (ushort_t*)(packed + E);        // 80 frags x 512 us = 80 KB
    int* chist   = (int*)(frg + 80 * 512);
    int* cbase   = chist + 256;                     // 257
    int* ccur    = cbase + 257;

    ushort_t* frg_inv = frg;
    ushort_t* frg_and = frg + 40 * 512;

    const int ntiles = (N + 15) / 16;
    const int NB     = (N + BSZ - 1) / BSZ;         // coarse buckets (<=256)
    const int cgrid  = (E + ACH - 1) / ACH;
    const int gp1    = (ntiles + 7) / 8;            // pass1: 4 waves x 2 tiles
    const int g45    = (ntiles + 7) / 8;            // mlp45: 4 waves x 2 tiles
    const int ggat   = (N + 7) / 8;                 // gather: 4 waves x 2 nodes

    hipMemsetAsync(chist, 0, 256 * sizeof(int), stream);

    // 1) coarse histogram || weight frag pre-pack
    prep_hist_k<<<cgrid + 20, 256, 0, stream>>>(dst, chist, iw1, iw2, iw3,
                                                aw1, aw2, aw3, frg, E, cgrid);
    // 2) coarse-bucket scan
    cscan_k<<<1, 256, 0, stream>>>(chist, cbase, ccur, NB, E);
    // 3) coarse bin pass
    coarse_bin_k<<<cgrid, 256, 0, stream>>>(src, dst, r, ccur, ebuf, E);
    // 4) fine CSR build || pass1 (invb = bf16(mlp_inv(feat)), featb = bf16(feat))
    pass1_fine_k<<<NB + gp1, 256, 0, stream>>>(feat, frg_inv, ib1, ib2, ib3,
                                               invb, featb, ebuf, cbase,
                                               offsets, packed, N, E, NB, ntiles);
    // 5) neighb = bf16(mean of messages by dst)
    gather_mean_k<<<ggat, 256, 0, stream>>>(featb, invb, offsets,
                                            packed, neighb, N);
    // 6) fused: res = mlp_and(neighb); out = inv ? mlp_inv(res) : res
    mlp45_k<<<g45, 256, 0, stream>>>(neighb, frg_and, frg_inv,
                                     ab1, ab2, ab3, ib1, ib2, ib3,
                                     (float*)d_out, inv, N, ntiles);
}